// Round 2
// 374.134 us; speedup vs baseline: 1.0179x; 1.0179x over previous
//
#include <hip/hip_runtime.h>

typedef unsigned short bf16_t;
typedef short short8 __attribute__((ext_vector_type(8)));
typedef float f32x4 __attribute__((ext_vector_type(4)));
typedef float f32x16 __attribute__((ext_vector_type(16)));
typedef unsigned int u32x4 __attribute__((ext_vector_type(4)));

static __device__ __forceinline__ unsigned short f2bf(float f) {
  unsigned int u = __float_as_uint(f);
  unsigned int r = (u + 0x7FFFu + ((u >> 16) & 1u)) >> 16;
  return (unsigned short)r;
}
static __device__ __forceinline__ float bf2f(unsigned short u) {
  return __uint_as_float((unsigned int)u << 16);
}
static __device__ __forceinline__ unsigned int cvt_pk_bf16(float lo, float hi) {
  unsigned int r;
  asm("v_cvt_pk_bf16_f32 %0, %1, %2" : "=v"(r) : "v"(lo), "v"(hi));
  return r;
}
static __device__ __forceinline__ void pl32swap(unsigned int& a, unsigned int& b) {
  // new_a[32..63] = old_b[0..31]; new_b[0..31] = old_a[32..63]
  asm("v_permlane32_swap_b32 %0, %1" : "+v"(a), "+v"(b));
}

__device__ __forceinline__ void gload_lds16(const void* g, void* l) {
  __builtin_amdgcn_global_load_lds((const __attribute__((address_space(1))) void*)g,
                                   (__attribute__((address_space(3))) void*)l,
                                   16, 0, 0);
}

// ---------------------------------------------------------------------------
// Fused prep: blocks [0,4096) transpose Wq/Wk/Wv/Wo (1024x1024 each);
// [4096,8192) W1 (1024x4096); [8192,12288) W2 (4096x1024);
// [12288,16384) LayerNorm rows of x.
// ---------------------------------------------------------------------------
__global__ __launch_bounds__(256) void prep_kernel(
    const float* __restrict__ Wq, const float* __restrict__ Wk,
    const float* __restrict__ Wv, const float* __restrict__ Wo,
    const float* __restrict__ W1, const float* __restrict__ W2,
    const float* __restrict__ x, const float* __restrict__ g1,
    const float* __restrict__ be1,
    bf16_t* __restrict__ WqkvT, bf16_t* __restrict__ W1T,
    bf16_t* __restrict__ W2T, bf16_t* __restrict__ xnb) {
  __shared__ float tile[32][33];
  const int bid = blockIdx.x;
  if (bid < 12288) {
    const float* src;
    bf16_t* dst;
    int rows, cols, bx, by;
    if (bid < 4096) {
      const int z = bid >> 10, r = bid & 1023;
      src = (z == 0) ? Wq : (z == 1) ? Wk : (z == 2) ? Wv : Wo;
      dst = WqkvT + (size_t)z * 1048576;
      rows = 1024; cols = 1024;
      bx = (r & 31) * 32; by = (r >> 5) * 32;
    } else if (bid < 8192) {
      const int r = bid - 4096;
      src = W1; dst = W1T; rows = 1024; cols = 4096;
      bx = (r & 127) * 32; by = (r >> 7) * 32;
    } else {
      const int r = bid - 8192;
      src = W2; dst = W2T; rows = 4096; cols = 1024;
      bx = (r & 31) * 32; by = (r >> 5) * 32;
    }
    const int tx = threadIdx.x & 31, ty = threadIdx.x >> 5;
#pragma unroll
    for (int i = 0; i < 32; i += 8)
      tile[ty + i][tx] = src[(size_t)(by + ty + i) * cols + (bx + tx)];
    __syncthreads();
#pragma unroll
    for (int i = 0; i < 32; i += 8)
      dst[(size_t)(bx + ty + i) * rows + (by + tx)] = f2bf(tile[tx][ty + i]);
  } else {
    const int row = bid - 12288;
    const int tid = threadIdx.x;
    const float4 v = reinterpret_cast<const float4*>(x + (size_t)row * 1024)[tid];
    float s = v.x + v.y + v.z + v.w;
    float ss = v.x * v.x + v.y * v.y + v.z * v.z + v.w * v.w;
#pragma unroll
    for (int off = 32; off; off >>= 1) {
      s += __shfl_xor(s, off, 64);
      ss += __shfl_xor(ss, off, 64);
    }
    float* red = &tile[0][0];
    const int wave = tid >> 6, lane = tid & 63;
    if (lane == 0) { red[wave] = s; red[4 + wave] = ss; }
    __syncthreads();
    const float mu = (red[0] + red[1] + red[2] + red[3]) * (1.f / 1024.f);
    const float ms = (red[4] + red[5] + red[6] + red[7]) * (1.f / 1024.f);
    const float rstd = rsqrtf(ms - mu * mu + 1e-5f);
    const float4 gg = reinterpret_cast<const float4*>(g1)[tid];
    const float4 bb = reinterpret_cast<const float4*>(be1)[tid];
    bf16_t* o = xnb + (size_t)row * 1024 + tid * 4;
    o[0] = f2bf((v.x - mu) * rstd * gg.x + bb.x);
    o[1] = f2bf((v.y - mu) * rstd * gg.y + bb.y);
    o[2] = f2bf((v.z - mu) * rstd * gg.z + bb.z);
    o[3] = f2bf((v.w - mu) * rstd * gg.w + bb.w);
  }
}

// ---------------------------------------------------------------------------
// LN2-combine: x2 = sum(4 bf16 partials)+bo+x ; x2 f32 out + xn2 = LN(x2) bf16
// ---------------------------------------------------------------------------
__global__ __launch_bounds__(256) void ln2_combine(const bf16_t* __restrict__ p,
                                                   const float* __restrict__ x,
                                                   const float* __restrict__ bo,
                                                   const float* __restrict__ g,
                                                   const float* __restrict__ be,
                                                   float* __restrict__ x2,
                                                   bf16_t* __restrict__ xn) {
  const int row = blockIdx.x;
  const int tid = threadIdx.x;
  const float4 xv = reinterpret_cast<const float4*>(x + (size_t)row * 1024)[tid];
  const float4 bb = reinterpret_cast<const float4*>(bo)[tid];
  float4 v = {bb.x + xv.x, bb.y + xv.y, bb.z + xv.z, bb.w + xv.w};
#pragma unroll
  for (int z = 0; z < 4; ++z) {
    const ushort4 a = reinterpret_cast<const ushort4*>(p + (size_t)z * 4194304 + (size_t)row * 1024)[tid];
    v.x += bf2f(a.x); v.y += bf2f(a.y); v.z += bf2f(a.z); v.w += bf2f(a.w);
  }
  reinterpret_cast<float4*>(x2 + (size_t)row * 1024)[tid] = v;
  float s = v.x + v.y + v.z + v.w;
  float ss = v.x * v.x + v.y * v.y + v.z * v.z + v.w * v.w;
#pragma unroll
  for (int off = 32; off; off >>= 1) {
    s += __shfl_xor(s, off, 64);
    ss += __shfl_xor(ss, off, 64);
  }
  __shared__ float red[8];
  const int wave = tid >> 6, lane = tid & 63;
  if (lane == 0) { red[wave] = s; red[4 + wave] = ss; }
  __syncthreads();
  const float mu = (red[0] + red[1] + red[2] + red[3]) * (1.f / 1024.f);
  const float ms = (red[4] + red[5] + red[6] + red[7]) * (1.f / 1024.f);
  const float rstd = rsqrtf(ms - mu * mu + 1e-5f);
  const float4 gg = reinterpret_cast<const float4*>(g)[tid];
  const float4 eb = reinterpret_cast<const float4*>(be)[tid];
  bf16_t* o = xn + (size_t)row * 1024 + tid * 4;
  o[0] = f2bf((v.x - mu) * rstd * gg.x + eb.x);
  o[1] = f2bf((v.y - mu) * rstd * gg.y + eb.y);
  o[2] = f2bf((v.z - mu) * rstd * gg.z + eb.z);
  o[3] = f2bf((v.w - mu) * rstd * gg.w + eb.w);
}

// ---------------------------------------------------------------------------
// FFN combine: out = bf(p0)+bf(p1)+bf(p2)+b2+x2
// ---------------------------------------------------------------------------
__global__ __launch_bounds__(256) void ffn_combine(const bf16_t* __restrict__ p0,
                                                   const bf16_t* __restrict__ p2,
                                                   const float* __restrict__ x2,
                                                   const float* __restrict__ b2,
                                                   float* __restrict__ out) {
  const int row = blockIdx.x;
  const int tid = threadIdx.x;
  const ushort4 a0 = reinterpret_cast<const ushort4*>(p0 + (size_t)row * 1024)[tid];
  const ushort4 a1 = reinterpret_cast<const ushort4*>(p0 + 4194304 + (size_t)row * 1024)[tid];
  const ushort4 a2 = reinterpret_cast<const ushort4*>(p2 + (size_t)row * 1024)[tid];
  const float4 xv = reinterpret_cast<const float4*>(x2 + (size_t)row * 1024)[tid];
  const float4 bb = reinterpret_cast<const float4*>(b2)[tid];
  float4 v;
  v.x = bf2f(a0.x) + bf2f(a1.x) + bf2f(a2.x) + bb.x + xv.x;
  v.y = bf2f(a0.y) + bf2f(a1.y) + bf2f(a2.y) + bb.y + xv.y;
  v.z = bf2f(a0.z) + bf2f(a1.z) + bf2f(a2.z) + bb.z + xv.z;
  v.w = bf2f(a0.w) + bf2f(a1.w) + bf2f(a2.w) + bb.w + xv.w;
  reinterpret_cast<float4*>(out + (size_t)row * 1024)[tid] = v;
}

// ---------------------------------------------------------------------------
// RoPE in place on bf16 q,k [B,H,S,64]; q scaled by (1/8)*log2(e).
// ---------------------------------------------------------------------------
__global__ __launch_bounds__(256) void rope_bf16(bf16_t* __restrict__ q,
                                                 bf16_t* __restrict__ k) {
  const int id = blockIdx.x * 256 + threadIdx.x;
  const int i = id & 31;
  const int s = (id >> 5) & 2047;
  const int bh = id >> 16;
  const float inv = exp2f((float)i * -0.41524101186f);
  float sn, cs;
  sincosf((float)s * inv, &sn, &cs);
  const size_t base = ((size_t)bh * 2048 + s) * 64 + 2 * i;
  unsigned int qp = *(unsigned int*)&q[base];
  unsigned int kp = *(unsigned int*)&k[base];
  const float q0 = bf2f(qp & 0xffff), q1 = bf2f(qp >> 16);
  const float k0 = bf2f(kp & 0xffff), k1 = bf2f(kp >> 16);
  const float qs = 0.18033688f;  // 0.125 * log2(e)
  const unsigned int qo =
      (unsigned int)f2bf((q0 * cs - q1 * sn) * qs) |
      ((unsigned int)f2bf((q0 * sn + q1 * cs) * qs) << 16);
  const unsigned int ko =
      (unsigned int)f2bf(k0 * cs - k1 * sn) |
      ((unsigned int)f2bf(k0 * sn + k1 * cs) << 16);
  *(unsigned int*)&q[base] = qo;
  *(unsigned int*)&k[base] = ko;
}

// ---------------------------------------------------------------------------
// V transpose: v [b,h,s,64] bf16 -> vt [b,h,64,2048] bf16
// ---------------------------------------------------------------------------
__global__ __launch_bounds__(256) void vtrans(const bf16_t* __restrict__ v,
                                              bf16_t* __restrict__ vt) {
  __shared__ bf16_t tile[32][33];
  const int bh = blockIdx.x;
  const int s0 = blockIdx.y * 32;
  const int d0 = blockIdx.z * 32;
  const int tx = threadIdx.x & 31, ty = threadIdx.x >> 5;
  const size_t base = (size_t)bh * (2048 * 64);
#pragma unroll
  for (int i = 0; i < 32; i += 8)
    tile[ty + i][tx] = v[base + (size_t)(s0 + ty + i) * 64 + d0 + tx];
  __syncthreads();
#pragma unroll
  for (int i = 0; i < 32; i += 8)
    vt[base + (size_t)(d0 + ty + i) * 2048 + s0 + tx] = tile[tx][ty + i];
}

// ---------------------------------------------------------------------------
// attn4: swapped-QK in-register-softmax flash attention, 32x32x16 MFMA.
// Per wave: 32 q-rows. QK^T computed as mfma(K, Q) so the C fragment puts a
// full q-row in each lane (col = lane&31 = q). Softmax entirely in registers;
// P -> bf16 A-fragment via v_cvt_pk_bf16_f32 + v_permlane32_swap_b32 (T12).
// K/V double-buffered in LDS (2-phase: stage t+1 overlaps compute of t).
// ---------------------------------------------------------------------------
__global__ __launch_bounds__(256) void attn4(const bf16_t* __restrict__ qb,
                                             const bf16_t* __restrict__ kb,
                                             const bf16_t* __restrict__ vt,
                                             bf16_t* __restrict__ out) {
  const int bh = blockIdx.x;
  const int tid = threadIdx.x, wave = tid >> 6, lane = tid & 63;
  const int l31 = lane & 31, hi = lane >> 5;
  const int q0 = blockIdx.y * 128 + wave * 32;
  const size_t kvb = (size_t)bh * (2048 * 64);

  __shared__ __align__(16) bf16_t Ks[2][4096];  // [kv 64][d 64], XOR-swizzled chunks
  __shared__ __align__(16) bf16_t Vs[2][4096];  // [d 64][kv 64], XOR-swizzled chunks
  __shared__ float lred[4][32];

  // Q as B-operand fragments: q = l31, d = st*16 + hi*8 + j
  short8 qf[4];
#pragma unroll
  for (int st = 0; st < 4; ++st)
    qf[st] = *(const short8*)&qb[kvb + (size_t)(q0 + l31) * 64 + st * 16 + hi * 8];

  f32x16 acc0, acc1;
#pragma unroll
  for (int r = 0; r < 16; ++r) { acc0[r] = 0.f; acc1[r] = 0.f; }
  float ls0 = 0.f, ls1 = 0.f, ls2 = 0.f, ls3 = 0.f;

  // prologue: stage tile 0 into buffer 0
#pragma unroll
  for (int j = 0; j < 2; ++j) {
    const int s = wave * 128 + j * 64 + lane;
    const int r = s >> 3;
    const int c = (s & 7) ^ (r & 7);
    gload_lds16(kb + kvb + (size_t)r * 64 + c * 8, &Ks[0][(size_t)s * 8]);
    gload_lds16(vt + kvb + (size_t)r * 2048 + c * 8, &Vs[0][(size_t)s * 8]);
  }
  __syncthreads();

  for (int t = 0; t < 2048; t += 64) {
    const int cur = (t >> 6) & 1;
    if (t + 64 < 2048) {  // prefetch next tile into other buffer
#pragma unroll
      for (int j = 0; j < 2; ++j) {
        const int s = wave * 128 + j * 64 + lane;
        const int r = s >> 3;
        const int c = (s & 7) ^ (r & 7);
        gload_lds16(kb + kvb + (size_t)(t + 64 + r) * 64 + c * 8, &Ks[cur ^ 1][(size_t)s * 8]);
        gload_lds16(vt + kvb + (size_t)r * 2048 + (t + 64) + c * 8, &Vs[cur ^ 1][(size_t)s * 8]);
      }
    }
    // QK^T, swapped operands: p[f] rows = kv (f*32 + frag-row), cols = q
    f32x16 p0, p1;
#pragma unroll
    for (int r = 0; r < 16; ++r) { p0[r] = 0.f; p1[r] = 0.f; }
#pragma unroll
    for (int st = 0; st < 4; ++st) {
      const int R0 = l31, R1 = 32 + l31;
      const short8 kf0 = *(const short8*)&Ks[cur][(size_t)(R0 * 8 + (((st << 1) | hi) ^ (R0 & 7))) * 8];
      const short8 kf1 = *(const short8*)&Ks[cur][(size_t)(R1 * 8 + (((st << 1) | hi) ^ (R1 & 7))) * 8];
      p0 = __builtin_amdgcn_mfma_f32_32x32x16_bf16(kf0, qf[st], p0, 0, 0, 0);
      p1 = __builtin_amdgcn_mfma_f32_32x32x16_bf16(kf1, qf[st], p1, 0, 0, 0);
    }
    // per 32-kv fragment: exp2 -> lsum -> pack to PV A-fragment -> PV MFMA
#pragma unroll
    for (int f = 0; f < 2; ++f) {
      f32x16& p = f ? p1 : p0;
      float e[16];
#pragma unroll
      for (int r = 0; r < 16; ++r) e[r] = exp2f(p[r]);
      ls0 += e[0] + e[1] + e[2] + e[3];
      ls1 += e[4] + e[5] + e[6] + e[7];
      ls2 += e[8] + e[9] + e[10] + e[11];
      ls3 += e[12] + e[13] + e[14] + e[15];
      // lane holds kv = (reg&3) + 8*(reg>>2) + 4*hi (within fragment).
      // A-frag needs kv = ks*16 + hi*8 + j. Pack adjacent-kv pairs, swap halves.
      unsigned int a0 = cvt_pk_bf16(e[0], e[1]), b0 = cvt_pk_bf16(e[4], e[5]);
      unsigned int a1 = cvt_pk_bf16(e[2], e[3]), b1 = cvt_pk_bf16(e[6], e[7]);
      unsigned int a2 = cvt_pk_bf16(e[8], e[9]), b2 = cvt_pk_bf16(e[12], e[13]);
      unsigned int a3 = cvt_pk_bf16(e[10], e[11]), b3 = cvt_pk_bf16(e[14], e[15]);
      pl32swap(a0, b0);
      pl32swap(a1, b1);
      pl32swap(a2, b2);
      pl32swap(a3, b3);
      const u32x4 w0 = {a0, a1, b0, b1};  // kstep 0: kv f*32 + [0,16)
      const u32x4 w1 = {a2, a3, b2, b3};  // kstep 1: kv f*32 + [16,32)
      const short8 pf0 = __builtin_bit_cast(short8, w0);
      const short8 pf1 = __builtin_bit_cast(short8, w1);
#pragma unroll
      for (int ks = 0; ks < 2; ++ks) {
        const short8 pf = ks ? pf1 : pf0;
        {
          const int R = l31;  // d 0..31
          const int C = (((f << 2) | (ks << 1) | hi) ^ (R & 7));
          const short8 vf = *(const short8*)&Vs[cur][(size_t)(R * 8 + C) * 8];
          acc0 = __builtin_amdgcn_mfma_f32_32x32x16_bf16(pf, vf, acc0, 0, 0, 0);
        }
        {
          const int R = 32 + l31;  // d 32..63
          const int C = (((f << 2) | (ks << 1) | hi) ^ (R & 7));
          const short8 vf = *(const short8*)&Vs[cur][(size_t)(R * 8 + C) * 8];
          acc1 = __builtin_amdgcn_mfma_f32_32x32x16_bf16(pf, vf, acc1, 0, 0, 0);
        }
      }
    }
    __syncthreads();
  }

  // row sums: lane has half its q-row's kv mass; partner half is at lane^32
  float lsum = (ls0 + ls1) + (ls2 + ls3);
  lsum += __shfl_xor(lsum, 32, 64);
  if (lane < 32) lred[wave][l31] = lsum;
  __syncthreads();

  const int b = bh >> 4, h = bh & 15;
#pragma unroll
  for (int r = 0; r < 16; ++r) {
    const int qrow = (r & 3) + 8 * (r >> 2) + 4 * hi;
    const float rl = 1.f / lred[wave][qrow];
    const size_t ro = (size_t)(b * 2048 + q0 + qrow) * 1024 + h * 64;
    out[ro + l31] = f2bf(acc0[r] * rl);
    out[ro + 32 + l31] = f2bf(acc1[r] * rl);
  }
}

// ---------------------------------------------------------------------------
// bf16 MFMA GEMM, C = A[M][K] @ BT[N][K]^T. BK=64 (2 k-chunks per barrier),
// XOR chunk swizzle (c ^= r&7) for conflict-free b128 frag reads, LDS-staged
// coalesced epilogue (dwordx4 stores). Split-K via blockIdx.z.
// ---------------------------------------------------------------------------
enum { MODE_QKV = 0, MODE_FF1 = 1, MODE_PART = 2 };

template <int MODE>
__global__ __launch_bounds__(256) void gemm_bt(
    const bf16_t* __restrict__ A, const bf16_t* __restrict__ BT,
    int M, int N, int K, int kspan,
    const float* __restrict__ bias0, const float* __restrict__ bias1,
    const float* __restrict__ bias2,
    bf16_t* __restrict__ ob0, bf16_t* __restrict__ ob1, bf16_t* __restrict__ ob2) {
  // loop phase: As 128x64 bf16 (16 KB) + Bs (16 KB); epilogue: 128x136 bf16 (34816 B)
  __shared__ __align__(16) char smem[34816];
  bf16_t* As = (bf16_t*)smem;
  bf16_t* Bs = (bf16_t*)(smem + 16384);
  const int tid = threadIdx.x;
  const int wave = tid >> 6, lane = tid & 63;
  const int row16 = lane & 15, quad = lane >> 4;
  const int m0 = blockIdx.x * 128, n0 = blockIdx.y * 128;
  const int wm = (wave & 1) << 6, wn = (wave >> 1) << 6;

  f32x4 acc[4][4];
#pragma unroll
  for (int i = 0; i < 4; ++i)
#pragma unroll
    for (int j = 0; j < 4; ++j) acc[i][j] = (f32x4){0.f, 0.f, 0.f, 0.f};

  const int kb = blockIdx.z * kspan;
  const int kend = (kb + kspan < K) ? kb + kspan : K;

  for (int k0 = kb; k0 < kend; k0 += 64) {
#pragma unroll
    for (int j = 0; j < 4; ++j) {
      const int s = j * 256 + tid;
      const int r = s >> 3;
      const int cg = ((s & 7) ^ (r & 7)) << 3;  // element offset of swizzled chunk
      gload_lds16(A + (size_t)(m0 + r) * K + k0 + cg, As + (size_t)s * 8);
      gload_lds16(BT + (size_t)(n0 + r) * K + k0 + cg, Bs + (size_t)s * 8);
    }
    __syncthreads();
    const int sw = row16 & 7;
#pragma unroll
    for (int kk = 0; kk < 2; ++kk) {
      short8 af[4], bfr[4];
#pragma unroll
      for (int mi = 0; mi < 4; ++mi)
        af[mi] = *(const short8*)&As[(size_t)(wm + mi * 16 + row16) * 64 + (((kk << 2) | quad) ^ sw) * 8];
#pragma unroll
      for (int ni = 0; ni < 4; ++ni)
        bfr[ni] = *(const short8*)&Bs[(size_t)(wn + ni * 16 + row16) * 64 + (((kk << 2) | quad) ^ sw) * 8];
#pragma unroll
      for (int mi = 0; mi < 4; ++mi)
#pragma unroll
        for (int ni = 0; ni < 4; ++ni)
          acc[mi][ni] =
              __builtin_amdgcn_mfma_f32_16x16x32_bf16(af[mi], bfr[ni], acc[mi][ni], 0, 0, 0);
    }
    __syncthreads();
  }

  // --- epilogue: bias/activation in regs -> bf16 tile in LDS -> coalesced stores
  bf16_t* ct = (bf16_t*)smem;  // [128][136]
#pragma unroll
  for (int mi = 0; mi < 4; ++mi)
#pragma unroll
    for (int ni = 0; ni < 4; ++ni) {
      const int gn = n0 + wn + ni * 16 + row16;
      float bsv = 0.f;
      if (MODE == MODE_QKV)
        bsv = (gn < 1024) ? bias0[gn] : (gn < 2048) ? bias1[gn - 1024] : bias2[gn - 2048];
      else if (MODE == MODE_FF1)
        bsv = bias0[gn];
#pragma unroll
      for (int r = 0; r < 4; ++r) {
        float c = acc[mi][ni][r] + bsv;
        if (MODE == MODE_FF1) c = fmaxf(c, 0.f);
        ct[(size_t)(wm + mi * 16 + quad * 4 + r) * 136 + wn + ni * 16 + row16] = f2bf(c);
      }
    }
  __syncthreads();
  const int lr0 = tid >> 4, lc = tid & 15;
#pragma unroll
  for (int i = 0; i < 8; ++i) {
    const int lr = i * 16 + lr0;
    const uint4 v = *(const uint4*)&ct[(size_t)lr * 136 + lc * 8];
    const int gm = m0 + lr;
    if (MODE == MODE_QKV) {
      const int nn = (n0 & 1023) + lc * 8;
      const int h = nn >> 6, d = nn & 63;
      const int b = gm >> 11, s = gm & 2047;
      bf16_t* dst = (n0 < 1024) ? ob0 : (n0 < 2048) ? ob1 : ob2;
      *(uint4*)&dst[(((size_t)b * 16 + h) * 2048 + s) * 64 + d] = v;
    } else if (MODE == MODE_FF1) {
      *(uint4*)&ob0[(size_t)gm * N + n0 + lc * 8] = v;
    } else {  // MODE_PART
      bf16_t* dst = (blockIdx.z == 2) ? ob1 : ob0 + (size_t)blockIdx.z * 4194304;
      *(uint4*)&dst[(size_t)gm * N + n0 + lc * 8] = v;
    }
  }
}

// ---------------------------------------------------------------------------
extern "C" void kernel_launch(void* const* d_in, const int* in_sizes, int n_in,
                              void* d_out, int out_size, void* d_ws, size_t ws_size,
                              hipStream_t stream) {
  const float* x = (const float*)d_in[0];
  const float* Wq = (const float*)d_in[1];
  const float* bq = (const float*)d_in[2];
  const float* Wk = (const float*)d_in[3];
  const float* bk = (const float*)d_in[4];
  const float* Wv = (const float*)d_in[5];
  const float* bv = (const float*)d_in[6];
  const float* Wo = (const float*)d_in[7];
  const float* bo = (const float*)d_in[8];
  const float* W1 = (const float*)d_in[9];
  const float* b1 = (const float*)d_in[10];
  const float* W2 = (const float*)d_in[11];
  const float* b2 = (const float*)d_in[12];
  const float* g1 = (const float*)d_in[13];
  const float* be1 = (const float*)d_in[14];
  const float* g2 = (const float*)d_in[15];
  const float* be2 = (const float*)d_in[16];
  float* out = (float*)d_out;

  char* ws = (char*)d_ws;
  size_t off = 0;
  auto alloc = [&](size_t bytes) {
    void* p = ws + off;
    off += (bytes + 255) & ~(size_t)255;
    return p;
  };
  bf16_t* WqkvT = (bf16_t*)alloc(3072ULL * 1024 * 2);  // [0,6MB)
  bf16_t* WoT = (bf16_t*)alloc(1024ULL * 1024 * 2);    // [6,8)
  bf16_t* W1T = (bf16_t*)alloc(4096ULL * 1024 * 2);    // [8,16)
  bf16_t* W2T = (bf16_t*)alloc(1024ULL * 4096 * 2);    // [16,24)
  bf16_t* xnb = (bf16_t*)alloc(4096ULL * 1024 * 2);    // [24,32) xn1/attn_out/xn2/FF2-partial2
  bf16_t* qb = (bf16_t*)alloc(4194304ULL * 2);         // [32,40)
  bf16_t* kb = (bf16_t*)alloc(4194304ULL * 2);         // [40,48)
  bf16_t* vraw = (bf16_t*)alloc(4194304ULL * 2);       // [48,56) V [b,h,s,d]
  bf16_t* vt = (bf16_t*)alloc(4194304ULL * 2);         // [56,64) V^T [b,h,d,s]
  bf16_t* h1 = qb;       // FF1 out [4096][4096] bf16 over [32,64)
  bf16_t* x2p = qb;      // X2 bf16 partials (4 x 8MB) over [32,64), pre-FF1
  bf16_t* ffp = WqkvT;   // FF2 partials 0,1 over dead weights [0,16)
  float* x2 = (float*)alloc(16777216ULL);              // [64,80)

  prep_kernel<<<16384, 256, 0, stream>>>(Wq, Wk, Wv, Wo, W1, W2, x, g1, be1,
                                         WqkvT, W1T, W2T, xnb);

  gemm_bt<MODE_QKV><<<dim3(32, 24, 1), 256, 0, stream>>>(xnb, WqkvT, 4096, 3072, 1024, 1024,
                                                         bq, bk, bv, qb, kb, vraw);

  rope_bf16<<<8192, 256, 0, stream>>>(qb, kb);

  vtrans<<<dim3(32, 64, 2), 256, 0, stream>>>(vraw, vt);

  attn4<<<dim3(32, 16), 256, 0, stream>>>(qb, kb, vt, xnb);

  // X2 = attn_out @ Wo, split-K=4 (kspan 256)
  gemm_bt<MODE_PART><<<dim3(32, 8, 4), 256, 0, stream>>>(xnb, WoT, 4096, 1024, 1024, 256,
                                                         nullptr, nullptr, nullptr,
                                                         x2p, x2p + 2 * 4194304, nullptr);

  ln2_combine<<<4096, 256, 0, stream>>>(x2p, x, bo, g2, be2, x2, xnb);

  gemm_bt<MODE_FF1><<<dim3(32, 32, 1), 256, 0, stream>>>(xnb, W1T, 4096, 4096, 1024, 1024,
                                                         b1, nullptr, nullptr,
                                                         h1, nullptr, nullptr);

  // FF2 = h1 @ W2, split-K=3 (1408/1408/1280; 64-multiples for BK=64)
  gemm_bt<MODE_PART><<<dim3(32, 8, 3), 256, 0, stream>>>(h1, W2T, 4096, 1024, 4096, 1408,
                                                         nullptr, nullptr, nullptr,
                                                         ffp, xnb, nullptr);

  ffn_combine<<<4096, 256, 0, stream>>>(ffp, xnb, x2, b2, out);
}

// Round 3
// 365.324 us; speedup vs baseline: 1.0425x; 1.0241x over previous
//
#include <hip/hip_runtime.h>

typedef unsigned short bf16_t;
typedef short short8 __attribute__((ext_vector_type(8)));
typedef float f32x4 __attribute__((ext_vector_type(4)));
typedef float f32x16 __attribute__((ext_vector_type(16)));
typedef unsigned int u32x4 __attribute__((ext_vector_type(4)));

static __device__ __forceinline__ unsigned short f2bf(float f) {
  unsigned int u = __float_as_uint(f);
  unsigned int r = (u + 0x7FFFu + ((u >> 16) & 1u)) >> 16;
  return (unsigned short)r;
}
static __device__ __forceinline__ float bf2f(unsigned short u) {
  return __uint_as_float((unsigned int)u << 16);
}
static __device__ __forceinline__ unsigned int cvt_pk_bf16(float lo, float hi) {
  unsigned int r;
  asm("v_cvt_pk_bf16_f32 %0, %1, %2" : "=v"(r) : "v"(lo), "v"(hi));
  return r;
}
static __device__ __forceinline__ void pl32swap(unsigned int& a, unsigned int& b) {
  // new_a[32..63] = old_b[0..31]; new_b[0..31] = old_a[32..63]
  asm("v_permlane32_swap_b32 %0, %1" : "+v"(a), "+v"(b));
}

__device__ __forceinline__ void gload_lds16(const void* g, void* l) {
  __builtin_amdgcn_global_load_lds((const __attribute__((address_space(1))) void*)g,
                                   (__attribute__((address_space(3))) void*)l,
                                   16, 0, 0);
}

// ---------------------------------------------------------------------------
// Fused prep: blocks [0,4096) transpose Wq/Wk/Wv/Wo (1024x1024 each);
// [4096,8192) W1 (1024x4096); [8192,12288) W2 (4096x1024);
// [12288,16384) LayerNorm rows of x.
// ---------------------------------------------------------------------------
__global__ __launch_bounds__(256) void prep_kernel(
    const float* __restrict__ Wq, const float* __restrict__ Wk,
    const float* __restrict__ Wv, const float* __restrict__ Wo,
    const float* __restrict__ W1, const float* __restrict__ W2,
    const float* __restrict__ x, const float* __restrict__ g1,
    const float* __restrict__ be1,
    bf16_t* __restrict__ WqkvT, bf16_t* __restrict__ W1T,
    bf16_t* __restrict__ W2T, bf16_t* __restrict__ xnb) {
  __shared__ float tile[32][33];
  const int bid = blockIdx.x;
  if (bid < 12288) {
    const float* src;
    bf16_t* dst;
    int rows, cols, bx, by;
    if (bid < 4096) {
      const int z = bid >> 10, r = bid & 1023;
      src = (z == 0) ? Wq : (z == 1) ? Wk : (z == 2) ? Wv : Wo;
      dst = WqkvT + (size_t)z * 1048576;
      rows = 1024; cols = 1024;
      bx = (r & 31) * 32; by = (r >> 5) * 32;
    } else if (bid < 8192) {
      const int r = bid - 4096;
      src = W1; dst = W1T; rows = 1024; cols = 4096;
      bx = (r & 127) * 32; by = (r >> 7) * 32;
    } else {
      const int r = bid - 8192;
      src = W2; dst = W2T; rows = 4096; cols = 1024;
      bx = (r & 31) * 32; by = (r >> 5) * 32;
    }
    const int tx = threadIdx.x & 31, ty = threadIdx.x >> 5;
#pragma unroll
    for (int i = 0; i < 32; i += 8)
      tile[ty + i][tx] = src[(size_t)(by + ty + i) * cols + (bx + tx)];
    __syncthreads();
#pragma unroll
    for (int i = 0; i < 32; i += 8)
      dst[(size_t)(bx + ty + i) * rows + (by + tx)] = f2bf(tile[tx][ty + i]);
  } else {
    const int row = bid - 12288;
    const int tid = threadIdx.x;
    const float4 v = reinterpret_cast<const float4*>(x + (size_t)row * 1024)[tid];
    float s = v.x + v.y + v.z + v.w;
    float ss = v.x * v.x + v.y * v.y + v.z * v.z + v.w * v.w;
#pragma unroll
    for (int off = 32; off; off >>= 1) {
      s += __shfl_xor(s, off, 64);
      ss += __shfl_xor(ss, off, 64);
    }
    float* red = &tile[0][0];
    const int wave = tid >> 6, lane = tid & 63;
    if (lane == 0) { red[wave] = s; red[4 + wave] = ss; }
    __syncthreads();
    const float mu = (red[0] + red[1] + red[2] + red[3]) * (1.f / 1024.f);
    const float ms = (red[4] + red[5] + red[6] + red[7]) * (1.f / 1024.f);
    const float rstd = rsqrtf(ms - mu * mu + 1e-5f);
    const float4 gg = reinterpret_cast<const float4*>(g1)[tid];
    const float4 bb = reinterpret_cast<const float4*>(be1)[tid];
    bf16_t* o = xnb + (size_t)row * 1024 + tid * 4;
    o[0] = f2bf((v.x - mu) * rstd * gg.x + bb.x);
    o[1] = f2bf((v.y - mu) * rstd * gg.y + bb.y);
    o[2] = f2bf((v.z - mu) * rstd * gg.z + bb.z);
    o[3] = f2bf((v.w - mu) * rstd * gg.w + bb.w);
  }
}

// ---------------------------------------------------------------------------
// LN2-combine: x2 = sum(4 bf16 partials)+bo+x ; x2 f32 out + xn2 = LN(x2) bf16
// ---------------------------------------------------------------------------
__global__ __launch_bounds__(256) void ln2_combine(const bf16_t* __restrict__ p,
                                                   const float* __restrict__ x,
                                                   const float* __restrict__ bo,
                                                   const float* __restrict__ g,
                                                   const float* __restrict__ be,
                                                   float* __restrict__ x2,
                                                   bf16_t* __restrict__ xn) {
  const int row = blockIdx.x;
  const int tid = threadIdx.x;
  const float4 xv = reinterpret_cast<const float4*>(x + (size_t)row * 1024)[tid];
  const float4 bb = reinterpret_cast<const float4*>(bo)[tid];
  float4 v = {bb.x + xv.x, bb.y + xv.y, bb.z + xv.z, bb.w + xv.w};
#pragma unroll
  for (int z = 0; z < 4; ++z) {
    const ushort4 a = reinterpret_cast<const ushort4*>(p + (size_t)z * 4194304 + (size_t)row * 1024)[tid];
    v.x += bf2f(a.x); v.y += bf2f(a.y); v.z += bf2f(a.z); v.w += bf2f(a.w);
  }
  reinterpret_cast<float4*>(x2 + (size_t)row * 1024)[tid] = v;
  float s = v.x + v.y + v.z + v.w;
  float ss = v.x * v.x + v.y * v.y + v.z * v.z + v.w * v.w;
#pragma unroll
  for (int off = 32; off; off >>= 1) {
    s += __shfl_xor(s, off, 64);
    ss += __shfl_xor(ss, off, 64);
  }
  __shared__ float red[8];
  const int wave = tid >> 6, lane = tid & 63;
  if (lane == 0) { red[wave] = s; red[4 + wave] = ss; }
  __syncthreads();
  const float mu = (red[0] + red[1] + red[2] + red[3]) * (1.f / 1024.f);
  const float ms = (red[4] + red[5] + red[6] + red[7]) * (1.f / 1024.f);
  const float rstd = rsqrtf(ms - mu * mu + 1e-5f);
  const float4 gg = reinterpret_cast<const float4*>(g)[tid];
  const float4 eb = reinterpret_cast<const float4*>(be)[tid];
  bf16_t* o = xn + (size_t)row * 1024 + tid * 4;
  o[0] = f2bf((v.x - mu) * rstd * gg.x + eb.x);
  o[1] = f2bf((v.y - mu) * rstd * gg.y + eb.y);
  o[2] = f2bf((v.z - mu) * rstd * gg.z + eb.z);
  o[3] = f2bf((v.w - mu) * rstd * gg.w + eb.w);
}

// ---------------------------------------------------------------------------
// FFN combine: out = bf(p0)+bf(p1)+bf(p2)+b2+x2
// ---------------------------------------------------------------------------
__global__ __launch_bounds__(256) void ffn_combine(const bf16_t* __restrict__ p0,
                                                   const bf16_t* __restrict__ p2,
                                                   const float* __restrict__ x2,
                                                   const float* __restrict__ b2,
                                                   float* __restrict__ out) {
  const int row = blockIdx.x;
  const int tid = threadIdx.x;
  const ushort4 a0 = reinterpret_cast<const ushort4*>(p0 + (size_t)row * 1024)[tid];
  const ushort4 a1 = reinterpret_cast<const ushort4*>(p0 + 4194304 + (size_t)row * 1024)[tid];
  const ushort4 a2 = reinterpret_cast<const ushort4*>(p2 + (size_t)row * 1024)[tid];
  const float4 xv = reinterpret_cast<const float4*>(x2 + (size_t)row * 1024)[tid];
  const float4 bb = reinterpret_cast<const float4*>(b2)[tid];
  float4 v;
  v.x = bf2f(a0.x) + bf2f(a1.x) + bf2f(a2.x) + bb.x + xv.x;
  v.y = bf2f(a0.y) + bf2f(a1.y) + bf2f(a2.y) + bb.y + xv.y;
  v.z = bf2f(a0.z) + bf2f(a1.z) + bf2f(a2.z) + bb.z + xv.z;
  v.w = bf2f(a0.w) + bf2f(a1.w) + bf2f(a2.w) + bb.w + xv.w;
  reinterpret_cast<float4*>(out + (size_t)row * 1024)[tid] = v;
}

// ---------------------------------------------------------------------------
// RoPE in place on bf16 q,k [B,H,S,64]; q scaled by (1/8)*log2(e).
// ---------------------------------------------------------------------------
__global__ __launch_bounds__(256) void rope_bf16(bf16_t* __restrict__ q,
                                                 bf16_t* __restrict__ k) {
  const int id = blockIdx.x * 256 + threadIdx.x;
  const int i = id & 31;
  const int s = (id >> 5) & 2047;
  const int bh = id >> 16;
  const float inv = exp2f((float)i * -0.41524101186f);
  float sn, cs;
  sincosf((float)s * inv, &sn, &cs);
  const size_t base = ((size_t)bh * 2048 + s) * 64 + 2 * i;
  unsigned int qp = *(unsigned int*)&q[base];
  unsigned int kp = *(unsigned int*)&k[base];
  const float q0 = bf2f(qp & 0xffff), q1 = bf2f(qp >> 16);
  const float k0 = bf2f(kp & 0xffff), k1 = bf2f(kp >> 16);
  const float qs = 0.18033688f;  // 0.125 * log2(e)
  const unsigned int qo =
      (unsigned int)f2bf((q0 * cs - q1 * sn) * qs) |
      ((unsigned int)f2bf((q0 * sn + q1 * cs) * qs) << 16);
  const unsigned int ko =
      (unsigned int)f2bf(k0 * cs - k1 * sn) |
      ((unsigned int)f2bf(k0 * sn + k1 * cs) << 16);
  *(unsigned int*)&q[base] = qo;
  *(unsigned int*)&k[base] = ko;
}

// ---------------------------------------------------------------------------
// V transpose: v [b,h,s,64] bf16 -> vt [b,h,64,2048] bf16
// ---------------------------------------------------------------------------
__global__ __launch_bounds__(256) void vtrans(const bf16_t* __restrict__ v,
                                              bf16_t* __restrict__ vt) {
  __shared__ bf16_t tile[32][33];
  const int bh = blockIdx.x;
  const int s0 = blockIdx.y * 32;
  const int d0 = blockIdx.z * 32;
  const int tx = threadIdx.x & 31, ty = threadIdx.x >> 5;
  const size_t base = (size_t)bh * (2048 * 64);
#pragma unroll
  for (int i = 0; i < 32; i += 8)
    tile[ty + i][tx] = v[base + (size_t)(s0 + ty + i) * 64 + d0 + tx];
  __syncthreads();
#pragma unroll
  for (int i = 0; i < 32; i += 8)
    vt[base + (size_t)(d0 + ty + i) * 2048 + s0 + tx] = tile[tx][ty + i];
}

// ---------------------------------------------------------------------------
// attn5: swapped-QK in-register-softmax flash attention, 32x32x16 MFMA.
// vs attn4: (1) launch_bounds(256,2) — grid caps at 2 waves/SIMD anyway, so
// free the register allocator; (2) KV loop unrolled x2 so the LDS buffer
// select is compile-time -> all 16 fragment addresses are loop-invariant and
// hoist to registers; (3) lsum via MFMA against an all-ones B fragment
// (row-sum lands in lacc with the epilogue's row mapping; kills 32 VALU adds
// per iter + the end shuffle/LDS reduce); (4) zero-C first MFMA kills the
// 32 p-init movs; (5) setprio(1) around MFMA clusters (T5).
// ---------------------------------------------------------------------------
__global__ __launch_bounds__(256, 2) void attn5(const bf16_t* __restrict__ qb,
                                                const bf16_t* __restrict__ kb,
                                                const bf16_t* __restrict__ vt,
                                                bf16_t* __restrict__ out) {
  const int bh = blockIdx.x;
  const int tid = threadIdx.x, wave = tid >> 6, lane = tid & 63;
  const int l31 = lane & 31, hi = lane >> 5;
  const int q0 = blockIdx.y * 128 + wave * 32;
  const size_t kvb = (size_t)bh * (2048 * 64);

  __shared__ __align__(16) bf16_t Ks[2][4096];  // [kv 64][d 64], XOR-swizzled chunks
  __shared__ __align__(16) bf16_t Vs[2][4096];  // [d 64][kv 64], XOR-swizzled chunks

  // Q as B-operand fragments: q = l31, d = st*16 + hi*8 + j
  short8 qf[4];
#pragma unroll
  for (int st = 0; st < 4; ++st)
    qf[st] = *(const short8*)&qb[kvb + (size_t)(q0 + l31) * 64 + st * 16 + hi * 8];

  // loop-invariant LDS fragment element indices
  int kidx[2][4];
  int vidx[2][2][2];
#pragma unroll
  for (int st = 0; st < 4; ++st) {
    const int R0 = l31, R1 = 32 + l31;
    kidx[0][st] = (R0 * 8 + (((st << 1) | hi) ^ (R0 & 7))) * 8;
    kidx[1][st] = (R1 * 8 + (((st << 1) | hi) ^ (R1 & 7))) * 8;
  }
#pragma unroll
  for (int f = 0; f < 2; ++f)
#pragma unroll
    for (int ks = 0; ks < 2; ++ks) {
      const int R0 = l31, R1 = 32 + l31;
      vidx[0][f][ks] = (R0 * 8 + (((f << 2) | (ks << 1) | hi) ^ (R0 & 7))) * 8;
      vidx[1][f][ks] = (R1 * 8 + (((f << 2) | (ks << 1) | hi) ^ (R1 & 7))) * 8;
    }

  short8 vones;  // bf16 1.0 x8 (ones B fragment for row-sum MFMA)
#pragma unroll
  for (int j = 0; j < 8; ++j) vones[j] = (short)0x3F80;

  f32x16 acc0 = {}, acc1 = {}, lacc = {};
  const f32x16 fz = {};

  // prologue: stage tile 0 into buffer 0
#pragma unroll
  for (int j = 0; j < 2; ++j) {
    const int s = wave * 128 + j * 64 + lane;
    const int r = s >> 3;
    const int c = (s & 7) ^ (r & 7);
    gload_lds16(kb + kvb + (size_t)r * 64 + c * 8, &Ks[0][(size_t)s * 8]);
    gload_lds16(vt + kvb + (size_t)r * 2048 + c * 8, &Vs[0][(size_t)s * 8]);
  }
  __syncthreads();

#define ATTN_TILE(BUF, TPREF, DOPREF)                                                     \
  {                                                                                       \
    if (DOPREF) {                                                                         \
      _Pragma("unroll") for (int j = 0; j < 2; ++j) {                                     \
        const int s = wave * 128 + j * 64 + lane;                                         \
        const int r = s >> 3;                                                             \
        const int c = (s & 7) ^ (r & 7);                                                  \
        gload_lds16(kb + kvb + (size_t)((TPREF) + r) * 64 + c * 8,                        \
                    &Ks[(BUF) ^ 1][(size_t)s * 8]);                                       \
        gload_lds16(vt + kvb + (size_t)r * 2048 + (TPREF) + c * 8,                        \
                    &Vs[(BUF) ^ 1][(size_t)s * 8]);                                       \
      }                                                                                   \
    }                                                                                     \
    short8 kfa[4], kfb[4];                                                                \
    _Pragma("unroll") for (int st = 0; st < 4; ++st) {                                    \
      kfa[st] = *(const short8*)&Ks[BUF][kidx[0][st]];                                    \
      kfb[st] = *(const short8*)&Ks[BUF][kidx[1][st]];                                    \
    }                                                                                     \
    __builtin_amdgcn_s_setprio(1);                                                        \
    f32x16 p0 = __builtin_amdgcn_mfma_f32_32x32x16_bf16(kfa[0], qf[0], fz, 0, 0, 0);      \
    f32x16 p1 = __builtin_amdgcn_mfma_f32_32x32x16_bf16(kfb[0], qf[0], fz, 0, 0, 0);      \
    _Pragma("unroll") for (int st = 1; st < 4; ++st) {                                    \
      p0 = __builtin_amdgcn_mfma_f32_32x32x16_bf16(kfa[st], qf[st], p0, 0, 0, 0);         \
      p1 = __builtin_amdgcn_mfma_f32_32x32x16_bf16(kfb[st], qf[st], p1, 0, 0, 0);         \
    }                                                                                     \
    __builtin_amdgcn_s_setprio(0);                                                        \
    _Pragma("unroll") for (int f = 0; f < 2; ++f) {                                       \
      f32x16& p = f ? p1 : p0;                                                            \
      float e[16];                                                                        \
      _Pragma("unroll") for (int r = 0; r < 16; ++r) e[r] = exp2f(p[r]);                  \
      unsigned int a0 = cvt_pk_bf16(e[0], e[1]), b0 = cvt_pk_bf16(e[4], e[5]);            \
      unsigned int a1 = cvt_pk_bf16(e[2], e[3]), b1 = cvt_pk_bf16(e[6], e[7]);            \
      unsigned int a2 = cvt_pk_bf16(e[8], e[9]), b2 = cvt_pk_bf16(e[12], e[13]);          \
      unsigned int a3 = cvt_pk_bf16(e[10], e[11]), b3 = cvt_pk_bf16(e[14], e[15]);        \
      pl32swap(a0, b0);                                                                   \
      pl32swap(a1, b1);                                                                   \
      pl32swap(a2, b2);                                                                   \
      pl32swap(a3, b3);                                                                   \
      const u32x4 w0 = {a0, a1, b0, b1};                                                  \
      const u32x4 w1 = {a2, a3, b2, b3};                                                  \
      const short8 pf0 = __builtin_bit_cast(short8, w0);                                  \
      const short8 pf1 = __builtin_bit_cast(short8, w1);                                  \
      const short8 vf00 = *(const short8*)&Vs[BUF][vidx[0][f][0]];                        \
      const short8 vf10 = *(const short8*)&Vs[BUF][vidx[1][f][0]];                        \
      const short8 vf01 = *(const short8*)&Vs[BUF][vidx[0][f][1]];                        \
      const short8 vf11 = *(const short8*)&Vs[BUF][vidx[1][f][1]];                        \
      __builtin_amdgcn_s_setprio(1);                                                      \
      lacc = __builtin_amdgcn_mfma_f32_32x32x16_bf16(pf0, vones, lacc, 0, 0, 0);          \
      acc0 = __builtin_amdgcn_mfma_f32_32x32x16_bf16(pf0, vf00, acc0, 0, 0, 0);           \
      acc1 = __builtin_amdgcn_mfma_f32_32x32x16_bf16(pf0, vf10, acc1, 0, 0, 0);           \
      lacc = __builtin_amdgcn_mfma_f32_32x32x16_bf16(pf1, vones, lacc, 0, 0, 0);          \
      acc0 = __builtin_amdgcn_mfma_f32_32x32x16_bf16(pf1, vf01, acc0, 0, 0, 0);           \
      acc1 = __builtin_amdgcn_mfma_f32_32x32x16_bf16(pf1, vf11, acc1, 0, 0, 0);           \
      __builtin_amdgcn_s_setprio(0);                                                      \
    }                                                                                     \
    __syncthreads();                                                                      \
  }

  for (int t = 0; t < 1920; t += 128) {
    ATTN_TILE(0, t + 64, 1)
    ATTN_TILE(1, t + 128, 1)
  }
  ATTN_TILE(0, 1984, 1)
  ATTN_TILE(1, 0, 0)
#undef ATTN_TILE

  const int b = bh >> 4, h = bh & 15;
#pragma unroll
  for (int r = 0; r < 16; ++r) {
    const int qrow = (r & 3) + 8 * (r >> 2) + 4 * hi;
    const float rl = 1.f / lacc[r];
    const size_t ro = (size_t)(b * 2048 + q0 + qrow) * 1024 + h * 64;
    out[ro + l31] = f2bf(acc0[r] * rl);
    out[ro + 32 + l31] = f2bf(acc1[r] * rl);
  }
}

// ---------------------------------------------------------------------------
// bf16 MFMA GEMM, C = A[M][K] @ BT[N][K]^T. BK=64 (2 k-chunks per barrier),
// XOR chunk swizzle (c ^= r&7) for conflict-free b128 frag reads, LDS-staged
// coalesced epilogue (dwordx4 stores). Split-K via blockIdx.z.
// ---------------------------------------------------------------------------
enum { MODE_QKV = 0, MODE_FF1 = 1, MODE_PART = 2 };

template <int MODE>
__global__ __launch_bounds__(256) void gemm_bt(
    const bf16_t* __restrict__ A, const bf16_t* __restrict__ BT,
    int M, int N, int K, int kspan,
    const float* __restrict__ bias0, const float* __restrict__ bias1,
    const float* __restrict__ bias2,
    bf16_t* __restrict__ ob0, bf16_t* __restrict__ ob1, bf16_t* __restrict__ ob2) {
  // loop phase: As 128x64 bf16 (16 KB) + Bs (16 KB); epilogue: 128x136 bf16 (34816 B)
  __shared__ __align__(16) char smem[34816];
  bf16_t* As = (bf16_t*)smem;
  bf16_t* Bs = (bf16_t*)(smem + 16384);
  const int tid = threadIdx.x;
  const int wave = tid >> 6, lane = tid & 63;
  const int row16 = lane & 15, quad = lane >> 4;
  const int m0 = blockIdx.x * 128, n0 = blockIdx.y * 128;
  const int wm = (wave & 1) << 6, wn = (wave >> 1) << 6;

  f32x4 acc[4][4];
#pragma unroll
  for (int i = 0; i < 4; ++i)
#pragma unroll
    for (int j = 0; j < 4; ++j) acc[i][j] = (f32x4){0.f, 0.f, 0.f, 0.f};

  const int kb = blockIdx.z * kspan;
  const int kend = (kb + kspan < K) ? kb + kspan : K;

  for (int k0 = kb; k0 < kend; k0 += 64) {
#pragma unroll
    for (int j = 0; j < 4; ++j) {
      const int s = j * 256 + tid;
      const int r = s >> 3;
      const int cg = ((s & 7) ^ (r & 7)) << 3;  // element offset of swizzled chunk
      gload_lds16(A + (size_t)(m0 + r) * K + k0 + cg, As + (size_t)s * 8);
      gload_lds16(BT + (size_t)(n0 + r) * K + k0 + cg, Bs + (size_t)s * 8);
    }
    __syncthreads();
    const int sw = row16 & 7;
#pragma unroll
    for (int kk = 0; kk < 2; ++kk) {
      short8 af[4], bfr[4];
#pragma unroll
      for (int mi = 0; mi < 4; ++mi)
        af[mi] = *(const short8*)&As[(size_t)(wm + mi * 16 + row16) * 64 + (((kk << 2) | quad) ^ sw) * 8];
#pragma unroll
      for (int ni = 0; ni < 4; ++ni)
        bfr[ni] = *(const short8*)&Bs[(size_t)(wn + ni * 16 + row16) * 64 + (((kk << 2) | quad) ^ sw) * 8];
#pragma unroll
      for (int mi = 0; mi < 4; ++mi)
#pragma unroll
        for (int ni = 0; ni < 4; ++ni)
          acc[mi][ni] =
              __builtin_amdgcn_mfma_f32_16x16x32_bf16(af[mi], bfr[ni], acc[mi][ni], 0, 0, 0);
    }
    __syncthreads();
  }

  // --- epilogue: bias/activation in regs -> bf16 tile in LDS -> coalesced stores
  bf16_t* ct = (bf16_t*)smem;  // [128][136]
#pragma unroll
  for (int mi = 0; mi < 4; ++mi)
#pragma unroll
    for (int ni = 0; ni < 4; ++ni) {
      const int gn = n0 + wn + ni * 16 + row16;
      float bsv = 0.f;
      if (MODE == MODE_QKV)
        bsv = (gn < 1024) ? bias0[gn] : (gn < 2048) ? bias1[gn - 1024] : bias2[gn - 2048];
      else if (MODE == MODE_FF1)
        bsv = bias0[gn];
#pragma unroll
      for (int r = 0; r < 4; ++r) {
        float c = acc[mi][ni][r] + bsv;
        if (MODE == MODE_FF1) c = fmaxf(c, 0.f);
        ct[(size_t)(wm + mi * 16 + quad * 4 + r) * 136 + wn + ni * 16 + row16] = f2bf(c);
      }
    }
  __syncthreads();
  const int lr0 = tid >> 4, lc = tid & 15;
#pragma unroll
  for (int i = 0; i < 8; ++i) {
    const int lr = i * 16 + lr0;
    const uint4 v = *(const uint4*)&ct[(size_t)lr * 136 + lc * 8];
    const int gm = m0 + lr;
    if (MODE == MODE_QKV) {
      const int nn = (n0 & 1023) + lc * 8;
      const int h = nn >> 6, d = nn & 63;
      const int b = gm >> 11, s = gm & 2047;
      bf16_t* dst = (n0 < 1024) ? ob0 : (n0 < 2048) ? ob1 : ob2;
      *(uint4*)&dst[(((size_t)b * 16 + h) * 2048 + s) * 64 + d] = v;
    } else if (MODE == MODE_FF1) {
      *(uint4*)&ob0[(size_t)gm * N + n0 + lc * 8] = v;
    } else {  // MODE_PART
      bf16_t* dst = (blockIdx.z == 2) ? ob1 : ob0 + (size_t)blockIdx.z * 4194304;
      *(uint4*)&dst[(size_t)gm * N + n0 + lc * 8] = v;
    }
  }
}

// ---------------------------------------------------------------------------
extern "C" void kernel_launch(void* const* d_in, const int* in_sizes, int n_in,
                              void* d_out, int out_size, void* d_ws, size_t ws_size,
                              hipStream_t stream) {
  const float* x = (const float*)d_in[0];
  const float* Wq = (const float*)d_in[1];
  const float* bq = (const float*)d_in[2];
  const float* Wk = (const float*)d_in[3];
  const float* bk = (const float*)d_in[4];
  const float* Wv = (const float*)d_in[5];
  const float* bv = (const float*)d_in[6];
  const float* Wo = (const float*)d_in[7];
  const float* bo = (const float*)d_in[8];
  const float* W1 = (const float*)d_in[9];
  const float* b1 = (const float*)d_in[10];
  const float* W2 = (const float*)d_in[11];
  const float* b2 = (const float*)d_in[12];
  const float* g1 = (const float*)d_in[13];
  const float* be1 = (const float*)d_in[14];
  const float* g2 = (const float*)d_in[15];
  const float* be2 = (const float*)d_in[16];
  float* out = (float*)d_out;

  char* ws = (char*)d_ws;
  size_t off = 0;
  auto alloc = [&](size_t bytes) {
    void* p = ws + off;
    off += (bytes + 255) & ~(size_t)255;
    return p;
  };
  bf16_t* WqkvT = (bf16_t*)alloc(3072ULL * 1024 * 2);  // [0,6MB)
  bf16_t* WoT = (bf16_t*)alloc(1024ULL * 1024 * 2);    // [6,8)
  bf16_t* W1T = (bf16_t*)alloc(4096ULL * 1024 * 2);    // [8,16)
  bf16_t* W2T = (bf16_t*)alloc(1024ULL * 4096 * 2);    // [16,24)
  bf16_t* xnb = (bf16_t*)alloc(4096ULL * 1024 * 2);    // [24,32) xn1/attn_out/xn2/FF2-partial2
  bf16_t* qb = (bf16_t*)alloc(4194304ULL * 2);         // [32,40)
  bf16_t* kb = (bf16_t*)alloc(4194304ULL * 2);         // [40,48)
  bf16_t* vraw = (bf16_t*)alloc(4194304ULL * 2);       // [48,56) V [b,h,s,d]
  bf16_t* vt = (bf16_t*)alloc(4194304ULL * 2);         // [56,64) V^T [b,h,d,s]
  bf16_t* h1 = qb;       // FF1 out [4096][4096] bf16 over [32,64)
  bf16_t* x2p = qb;      // X2 bf16 partials (4 x 8MB) over [32,64), pre-FF1
  bf16_t* ffp = WqkvT;   // FF2 partials 0,1 over dead weights [0,16)
  float* x2 = (float*)alloc(16777216ULL);              // [64,80)

  prep_kernel<<<16384, 256, 0, stream>>>(Wq, Wk, Wv, Wo, W1, W2, x, g1, be1,
                                         WqkvT, W1T, W2T, xnb);

  gemm_bt<MODE_QKV><<<dim3(32, 24, 1), 256, 0, stream>>>(xnb, WqkvT, 4096, 3072, 1024, 1024,
                                                         bq, bk, bv, qb, kb, vraw);

  rope_bf16<<<8192, 256, 0, stream>>>(qb, kb);

  vtrans<<<dim3(32, 64, 2), 256, 0, stream>>>(vraw, vt);

  attn5<<<dim3(32, 16), 256, 0, stream>>>(qb, kb, vt, xnb);

  // X2 = attn_out @ Wo, split-K=4 (kspan 256)
  gemm_bt<MODE_PART><<<dim3(32, 8, 4), 256, 0, stream>>>(xnb, WoT, 4096, 1024, 1024, 256,
                                                         nullptr, nullptr, nullptr,
                                                         x2p, x2p + 2 * 4194304, nullptr);

  ln2_combine<<<4096, 256, 0, stream>>>(x2p, x, bo, g2, be2, x2, xnb);

  gemm_bt<MODE_FF1><<<dim3(32, 32, 1), 256, 0, stream>>>(xnb, W1T, 4096, 4096, 1024, 1024,
                                                         b1, nullptr, nullptr,
                                                         h1, nullptr, nullptr);

  // FF2 = h1 @ W2, split-K=3 (1408/1408/1280; 64-multiples for BK=64)
  gemm_bt<MODE_PART><<<dim3(32, 8, 3), 256, 0, stream>>>(h1, W2T, 4096, 1024, 4096, 1408,
                                                         nullptr, nullptr, nullptr,
                                                         ffp, xnb, nullptr);

  ffn_combine<<<4096, 256, 0, stream>>>(ffp, xnb, x2, b2, out);
}

// Round 5
// 364.664 us; speedup vs baseline: 1.0444x; 1.0018x over previous
//
#include <hip/hip_runtime.h>

typedef unsigned short bf16_t;
typedef short short8 __attribute__((ext_vector_type(8)));
typedef float f32x4 __attribute__((ext_vector_type(4)));
typedef float f32x16 __attribute__((ext_vector_type(16)));
typedef unsigned int u32x4 __attribute__((ext_vector_type(4)));

static __device__ __forceinline__ unsigned short f2bf(float f) {
  unsigned int u = __float_as_uint(f);
  unsigned int r = (u + 0x7FFFu + ((u >> 16) & 1u)) >> 16;
  return (unsigned short)r;
}
static __device__ __forceinline__ float bf2f(unsigned short u) {
  return __uint_as_float((unsigned int)u << 16);
}
static __device__ __forceinline__ unsigned int cvt_pk_bf16(float lo, float hi) {
  unsigned int r;
  asm("v_cvt_pk_bf16_f32 %0, %1, %2" : "=v"(r) : "v"(lo), "v"(hi));
  return r;
}
static __device__ __forceinline__ void pl32swap(unsigned int& a, unsigned int& b) {
  // new_a[32..63] = old_b[0..31]; new_b[0..31] = old_a[32..63]
  asm("v_permlane32_swap_b32 %0, %1" : "+v"(a), "+v"(b));
}

__device__ __forceinline__ void gload_lds16(const void* g, void* l) {
  __builtin_amdgcn_global_load_lds((const __attribute__((address_space(1))) void*)g,
                                   (__attribute__((address_space(3))) void*)l,
                                   16, 0, 0);
}

// ---------------------------------------------------------------------------
// Fused prep: blocks [0,4096) transpose Wq/Wk/Wv/Wo (1024x1024 each);
// [4096,8192) W1 (1024x4096); [8192,12288) W2 (4096x1024);
// [12288,16384) LayerNorm rows of x.
// ---------------------------------------------------------------------------
__global__ __launch_bounds__(256) void prep_kernel(
    const float* __restrict__ Wq, const float* __restrict__ Wk,
    const float* __restrict__ Wv, const float* __restrict__ Wo,
    const float* __restrict__ W1, const float* __restrict__ W2,
    const float* __restrict__ x, const float* __restrict__ g1,
    const float* __restrict__ be1,
    bf16_t* __restrict__ WqkvT, bf16_t* __restrict__ W1T,
    bf16_t* __restrict__ W2T, bf16_t* __restrict__ xnb) {
  __shared__ float tile[32][33];
  const int bid = blockIdx.x;
  if (bid < 12288) {
    const float* src;
    bf16_t* dst;
    int rows, cols, bx, by;
    if (bid < 4096) {
      const int z = bid >> 10, r = bid & 1023;
      src = (z == 0) ? Wq : (z == 1) ? Wk : (z == 2) ? Wv : Wo;
      dst = WqkvT + (size_t)z * 1048576;
      rows = 1024; cols = 1024;
      bx = (r & 31) * 32; by = (r >> 5) * 32;
    } else if (bid < 8192) {
      const int r = bid - 4096;
      src = W1; dst = W1T; rows = 1024; cols = 4096;
      bx = (r & 127) * 32; by = (r >> 7) * 32;
    } else {
      const int r = bid - 8192;
      src = W2; dst = W2T; rows = 4096; cols = 1024;
      bx = (r & 31) * 32; by = (r >> 5) * 32;
    }
    const int tx = threadIdx.x & 31, ty = threadIdx.x >> 5;
#pragma unroll
    for (int i = 0; i < 32; i += 8)
      tile[ty + i][tx] = src[(size_t)(by + ty + i) * cols + (bx + tx)];
    __syncthreads();
#pragma unroll
    for (int i = 0; i < 32; i += 8)
      dst[(size_t)(bx + ty + i) * rows + (by + tx)] = f2bf(tile[tx][ty + i]);
  } else {
    const int row = bid - 12288;
    const int tid = threadIdx.x;
    const float4 v = reinterpret_cast<const float4*>(x + (size_t)row * 1024)[tid];
    float s = v.x + v.y + v.z + v.w;
    float ss = v.x * v.x + v.y * v.y + v.z * v.z + v.w * v.w;
#pragma unroll
    for (int off = 32; off; off >>= 1) {
      s += __shfl_xor(s, off, 64);
      ss += __shfl_xor(ss, off, 64);
    }
    float* red = &tile[0][0];
    const int wave = tid >> 6, lane = tid & 63;
    if (lane == 0) { red[wave] = s; red[4 + wave] = ss; }
    __syncthreads();
    const float mu = (red[0] + red[1] + red[2] + red[3]) * (1.f / 1024.f);
    const float ms = (red[4] + red[5] + red[6] + red[7]) * (1.f / 1024.f);
    const float rstd = rsqrtf(ms - mu * mu + 1e-5f);
    const float4 gg = reinterpret_cast<const float4*>(g1)[tid];
    const float4 bb = reinterpret_cast<const float4*>(be1)[tid];
    bf16_t* o = xnb + (size_t)row * 1024 + tid * 4;
    o[0] = f2bf((v.x - mu) * rstd * gg.x + bb.x);
    o[1] = f2bf((v.y - mu) * rstd * gg.y + bb.y);
    o[2] = f2bf((v.z - mu) * rstd * gg.z + bb.z);
    o[3] = f2bf((v.w - mu) * rstd * gg.w + bb.w);
  }
}

// ---------------------------------------------------------------------------
// LN2-combine: x2 = sum(4 bf16 partials)+bo+x ; x2 f32 out + xn2 = LN(x2) bf16
// ---------------------------------------------------------------------------
__global__ __launch_bounds__(256) void ln2_combine(const bf16_t* __restrict__ p,
                                                   const float* __restrict__ x,
                                                   const float* __restrict__ bo,
                                                   const float* __restrict__ g,
                                                   const float* __restrict__ be,
                                                   float* __restrict__ x2,
                                                   bf16_t* __restrict__ xn) {
  const int row = blockIdx.x;
  const int tid = threadIdx.x;
  const float4 xv = reinterpret_cast<const float4*>(x + (size_t)row * 1024)[tid];
  const float4 bb = reinterpret_cast<const float4*>(bo)[tid];
  float4 v = {bb.x + xv.x, bb.y + xv.y, bb.z + xv.z, bb.w + xv.w};
#pragma unroll
  for (int z = 0; z < 4; ++z) {
    const ushort4 a = reinterpret_cast<const ushort4*>(p + (size_t)z * 4194304 + (size_t)row * 1024)[tid];
    v.x += bf2f(a.x); v.y += bf2f(a.y); v.z += bf2f(a.z); v.w += bf2f(a.w);
  }
  reinterpret_cast<float4*>(x2 + (size_t)row * 1024)[tid] = v;
  float s = v.x + v.y + v.z + v.w;
  float ss = v.x * v.x + v.y * v.y + v.z * v.z + v.w * v.w;
#pragma unroll
  for (int off = 32; off; off >>= 1) {
    s += __shfl_xor(s, off, 64);
    ss += __shfl_xor(ss, off, 64);
  }
  __shared__ float red[8];
  const int wave = tid >> 6, lane = tid & 63;
  if (lane == 0) { red[wave] = s; red[4 + wave] = ss; }
  __syncthreads();
  const float mu = (red[0] + red[1] + red[2] + red[3]) * (1.f / 1024.f);
  const float ms = (red[4] + red[5] + red[6] + red[7]) * (1.f / 1024.f);
  const float rstd = rsqrtf(ms - mu * mu + 1e-5f);
  const float4 gg = reinterpret_cast<const float4*>(g)[tid];
  const float4 eb = reinterpret_cast<const float4*>(be)[tid];
  bf16_t* o = xn + (size_t)row * 1024 + tid * 4;
  o[0] = f2bf((v.x - mu) * rstd * gg.x + eb.x);
  o[1] = f2bf((v.y - mu) * rstd * gg.y + eb.y);
  o[2] = f2bf((v.z - mu) * rstd * gg.z + eb.z);
  o[3] = f2bf((v.w - mu) * rstd * gg.w + eb.w);
}

// ---------------------------------------------------------------------------
// FFN combine: out = bf(p0)+bf(p1)+bf(p2)+b2+x2
// ---------------------------------------------------------------------------
__global__ __launch_bounds__(256) void ffn_combine(const bf16_t* __restrict__ p0,
                                                   const bf16_t* __restrict__ p2,
                                                   const float* __restrict__ x2,
                                                   const float* __restrict__ b2,
                                                   float* __restrict__ out) {
  const int row = blockIdx.x;
  const int tid = threadIdx.x;
  const ushort4 a0 = reinterpret_cast<const ushort4*>(p0 + (size_t)row * 1024)[tid];
  const ushort4 a1 = reinterpret_cast<const ushort4*>(p0 + 4194304 + (size_t)row * 1024)[tid];
  const ushort4 a2 = reinterpret_cast<const ushort4*>(p2 + (size_t)row * 1024)[tid];
  const float4 xv = reinterpret_cast<const float4*>(x2 + (size_t)row * 1024)[tid];
  const float4 bb = reinterpret_cast<const float4*>(b2)[tid];
  float4 v;
  v.x = bf2f(a0.x) + bf2f(a1.x) + bf2f(a2.x) + bb.x + xv.x;
  v.y = bf2f(a0.y) + bf2f(a1.y) + bf2f(a2.y) + bb.y + xv.y;
  v.z = bf2f(a0.z) + bf2f(a1.z) + bf2f(a2.z) + bb.z + xv.z;
  v.w = bf2f(a0.w) + bf2f(a1.w) + bf2f(a2.w) + bb.w + xv.w;
  reinterpret_cast<float4*>(out + (size_t)row * 1024)[tid] = v;
}

// ---------------------------------------------------------------------------
// RoPE in place on bf16 q,k [B,H,S,64]; q scaled by (1/8)*log2(e).
// ---------------------------------------------------------------------------
__global__ __launch_bounds__(256) void rope_bf16(bf16_t* __restrict__ q,
                                                 bf16_t* __restrict__ k) {
  const int id = blockIdx.x * 256 + threadIdx.x;
  const int i = id & 31;
  const int s = (id >> 5) & 2047;
  const int bh = id >> 16;
  const float inv = exp2f((float)i * -0.41524101186f);
  float sn, cs;
  sincosf((float)s * inv, &sn, &cs);
  const size_t base = ((size_t)bh * 2048 + s) * 64 + 2 * i;
  unsigned int qp = *(unsigned int*)&q[base];
  unsigned int kp = *(unsigned int*)&k[base];
  const float q0 = bf2f(qp & 0xffff), q1 = bf2f(qp >> 16);
  const float k0 = bf2f(kp & 0xffff), k1 = bf2f(kp >> 16);
  const float qs = 0.18033688f;  // 0.125 * log2(e)
  const unsigned int qo =
      (unsigned int)f2bf((q0 * cs - q1 * sn) * qs) |
      ((unsigned int)f2bf((q0 * sn + q1 * cs) * qs) << 16);
  const unsigned int ko =
      (unsigned int)f2bf(k0 * cs - k1 * sn) |
      ((unsigned int)f2bf(k0 * sn + k1 * cs) << 16);
  *(unsigned int*)&q[base] = qo;
  *(unsigned int*)&k[base] = ko;
}

// ---------------------------------------------------------------------------
// V transpose: v [b,h,s,64] bf16 -> vt [b,h,64,2048] bf16
// ---------------------------------------------------------------------------
__global__ __launch_bounds__(256) void vtrans(const bf16_t* __restrict__ v,
                                              bf16_t* __restrict__ vt) {
  __shared__ bf16_t tile[32][33];
  const int bh = blockIdx.x;
  const int s0 = blockIdx.y * 32;
  const int d0 = blockIdx.z * 32;
  const int tx = threadIdx.x & 31, ty = threadIdx.x >> 5;
  const size_t base = (size_t)bh * (2048 * 64);
#pragma unroll
  for (int i = 0; i < 32; i += 8)
    tile[ty + i][tx] = v[base + (size_t)(s0 + ty + i) * 64 + d0 + tx];
  __syncthreads();
#pragma unroll
  for (int i = 0; i < 32; i += 8)
    vt[base + (size_t)(d0 + ty + i) * 2048 + s0 + tx] = tile[tx][ty + i];
}

// ---------------------------------------------------------------------------
// attn6: swapped-QK in-register-softmax flash attention, 32x32x16 MFMA.
// vs attn5: KVBLK=128 compound tiles (2x64 sub-tiles per barrier phase),
// source-ordered QK(t0),QK(t1),SMPV(t0),SMPV(t1) so softmax VALU of one
// sub-tile overlaps MFMA of the other; raw s_barrier + counted vmcnt(8)
// (T4) so stage loads stay in flight across barriers (no compiler vmcnt(0)
// drain); double-buffered 64 KB LDS, 2 blocks/CU.
// ---------------------------------------------------------------------------
__global__ __launch_bounds__(256, 2) void attn6(const bf16_t* __restrict__ qb,
                                                const bf16_t* __restrict__ kb,
                                                const bf16_t* __restrict__ vt,
                                                bf16_t* __restrict__ out) {
  const int bh = blockIdx.x;
  const int tid = threadIdx.x, wave = tid >> 6, lane = tid & 63;
  const int l31 = lane & 31, hi = lane >> 5;
  const int q0 = blockIdx.y * 128 + wave * 32;
  const size_t kvb = (size_t)bh * (2048 * 64);

  __shared__ __align__(16) bf16_t Ks[2][2][4096];  // [dbuf][sub][kv64 x d64] swizzled
  __shared__ __align__(16) bf16_t Vs[2][2][4096];  // [dbuf][sub][d64 x kv64] swizzled

  // Q as B-operand fragments: q = l31, d = st*16 + hi*8 + j
  short8 qf[4];
#pragma unroll
  for (int st = 0; st < 4; ++st)
    qf[st] = *(const short8*)&qb[kvb + (size_t)(q0 + l31) * 64 + st * 16 + hi * 8];

  // loop-invariant LDS fragment element indices (within one 64x64 sub-tile)
  int kidx[2][4];
  int vidx[2][2][2];
#pragma unroll
  for (int st = 0; st < 4; ++st) {
    const int R0 = l31, R1 = 32 + l31;
    kidx[0][st] = (R0 * 8 + (((st << 1) | hi) ^ (R0 & 7))) * 8;
    kidx[1][st] = (R1 * 8 + (((st << 1) | hi) ^ (R1 & 7))) * 8;
  }
#pragma unroll
  for (int f = 0; f < 2; ++f)
#pragma unroll
    for (int ks = 0; ks < 2; ++ks) {
      const int R0 = l31, R1 = 32 + l31;
      vidx[0][f][ks] = (R0 * 8 + (((f << 2) | (ks << 1) | hi) ^ (R0 & 7))) * 8;
      vidx[1][f][ks] = (R1 * 8 + (((f << 2) | (ks << 1) | hi) ^ (R1 & 7))) * 8;
    }

  short8 vones;  // bf16 1.0 x8 (ones B fragment for row-sum MFMA)
#pragma unroll
  for (int j = 0; j < 8; ++j) vones[j] = (short)0x3F80;

  f32x16 acc0 = {}, acc1 = {}, lacc = {};
  const f32x16 fz = {};

// stage compound tile (kv base T0, 128 wide) into dbuf DST: 8 gload_lds/wave
#define STAGE(DST, T0)                                                                     \
  {                                                                                        \
    _Pragma("unroll") for (int sub = 0; sub < 2; ++sub) {                                  \
      _Pragma("unroll") for (int j = 0; j < 2; ++j) {                                      \
        const int s = wave * 128 + j * 64 + lane;                                          \
        const int r = s >> 3;                                                              \
        const int c = (s & 7) ^ (r & 7);                                                   \
        gload_lds16(kb + kvb + (size_t)((T0) + sub * 64 + r) * 64 + c * 8,                 \
                    &Ks[DST][sub][(size_t)s * 8]);                                         \
        gload_lds16(vt + kvb + (size_t)r * 2048 + (T0) + sub * 64 + c * 8,                 \
                    &Vs[DST][sub][(size_t)s * 8]);                                         \
      }                                                                                    \
    }                                                                                      \
  }

#define QK(BUF, SUB, P0, P1)                                                               \
  {                                                                                        \
    short8 kfa[4], kfb[4];                                                                 \
    _Pragma("unroll") for (int st = 0; st < 4; ++st) {                                     \
      kfa[st] = *(const short8*)&Ks[BUF][SUB][kidx[0][st]];                                \
      kfb[st] = *(const short8*)&Ks[BUF][SUB][kidx[1][st]];                                \
    }                                                                                      \
    __builtin_amdgcn_s_setprio(1);                                                         \
    P0 = __builtin_amdgcn_mfma_f32_32x32x16_bf16(kfa[0], qf[0], fz, 0, 0, 0);              \
    P1 = __builtin_amdgcn_mfma_f32_32x32x16_bf16(kfb[0], qf[0], fz, 0, 0, 0);              \
    _Pragma("unroll") for (int st = 1; st < 4; ++st) {                                     \
      P0 = __builtin_amdgcn_mfma_f32_32x32x16_bf16(kfa[st], qf[st], P0, 0, 0, 0);          \
      P1 = __builtin_amdgcn_mfma_f32_32x32x16_bf16(kfb[st], qf[st], P1, 0, 0, 0);          \
    }                                                                                      \
    __builtin_amdgcn_s_setprio(0);                                                         \
  }

#define SMPV(BUF, SUB, P0, P1)                                                             \
  {                                                                                        \
    _Pragma("unroll") for (int f = 0; f < 2; ++f) {                                        \
      f32x16& p = f ? P1 : P0;                                                             \
      float e[16];                                                                         \
      _Pragma("unroll") for (int r = 0; r < 16; ++r) e[r] = exp2f(p[r]);                   \
      unsigned int a0 = cvt_pk_bf16(e[0], e[1]), b0 = cvt_pk_bf16(e[4], e[5]);             \
      unsigned int a1 = cvt_pk_bf16(e[2], e[3]), b1 = cvt_pk_bf16(e[6], e[7]);             \
      unsigned int a2 = cvt_pk_bf16(e[8], e[9]), b2 = cvt_pk_bf16(e[12], e[13]);           \
      unsigned int a3 = cvt_pk_bf16(e[10], e[11]), b3 = cvt_pk_bf16(e[14], e[15]);         \
      pl32swap(a0, b0);                                                                    \
      pl32swap(a1, b1);                                                                    \
      pl32swap(a2, b2);                                                                    \
      pl32swap(a3, b3);                                                                    \
      const u32x4 w0 = {a0, a1, b0, b1};                                                   \
      const u32x4 w1 = {a2, a3, b2, b3};                                                   \
      const short8 pf0 = __builtin_bit_cast(short8, w0);                                   \
      const short8 pf1 = __builtin_bit_cast(short8, w1);                                   \
      const short8 vf00 = *(const short8*)&Vs[BUF][SUB][vidx[0][f][0]];                    \
      const short8 vf10 = *(const short8*)&Vs[BUF][SUB][vidx[1][f][0]];                    \
      const short8 vf01 = *(const short8*)&Vs[BUF][SUB][vidx[0][f][1]];                    \
      const short8 vf11 = *(const short8*)&Vs[BUF][SUB][vidx[1][f][1]];                    \
      __builtin_amdgcn_s_setprio(1);                                                       \
      lacc = __builtin_amdgcn_mfma_f32_32x32x16_bf16(pf0, vones, lacc, 0, 0, 0);           \
      acc0 = __builtin_amdgcn_mfma_f32_32x32x16_bf16(pf0, vf00, acc0, 0, 0, 0);            \
      acc1 = __builtin_amdgcn_mfma_f32_32x32x16_bf16(pf0, vf10, acc1, 0, 0, 0);            \
      lacc = __builtin_amdgcn_mfma_f32_32x32x16_bf16(pf1, vones, lacc, 0, 0, 0);           \
      acc0 = __builtin_amdgcn_mfma_f32_32x32x16_bf16(pf1, vf01, acc0, 0, 0, 0);            \
      acc1 = __builtin_amdgcn_mfma_f32_32x32x16_bf16(pf1, vf11, acc1, 0, 0, 0);            \
      __builtin_amdgcn_s_setprio(0);                                                       \
    }                                                                                      \
  }

// compound iter: stage next compound (if any), wait prev stage, barrier,
// compute both sub-tiles with cross-subtile pipelining, WAR barrier.
#define CITER(BUF, NT0, DOPREF)                                                            \
  {                                                                                        \
    if (DOPREF) {                                                                          \
      STAGE((BUF) ^ 1, NT0);                                                               \
      asm volatile("s_waitcnt vmcnt(8)" ::: "memory");                                     \
    } else {                                                                               \
      asm volatile("s_waitcnt vmcnt(0)" ::: "memory");                                     \
    }                                                                                      \
    __builtin_amdgcn_s_barrier();                                                          \
    asm volatile("" ::: "memory");                                                         \
    f32x16 pa0, pa1, pb0, pb1;                                                             \
    QK(BUF, 0, pa0, pa1);                                                                  \
    QK(BUF, 1, pb0, pb1);                                                                  \
    SMPV(BUF, 0, pa0, pa1);                                                                \
    SMPV(BUF, 1, pb0, pb1);                                                                \
    asm volatile("" ::: "memory");                                                         \
    __builtin_amdgcn_s_barrier();                                                          \
    asm volatile("" ::: "memory");                                                         \
  }

  // prologue: stage compound 0 (kv 0..127) into dbuf 0
  STAGE(0, 0);

  for (int k = 0; k < 7; ++k) {
    CITER(0, (2 * k + 1) * 128, 1)
    CITER(1, (2 * k + 2) * 128, 1)
  }
  CITER(0, 1920, 1)
  CITER(1, 0, 0)
#undef CITER
#undef SMPV
#undef QK
#undef STAGE

  const int b = bh >> 4, h = bh & 15;
#pragma unroll
  for (int r = 0; r < 16; ++r) {
    const int qrow = (r & 3) + 8 * (r >> 2) + 4 * hi;
    const float rl = 1.f / lacc[r];
    const size_t ro = (size_t)(b * 2048 + q0 + qrow) * 1024 + h * 64;
    out[ro + l31] = f2bf(acc0[r] * rl);
    out[ro + 32 + l31] = f2bf(acc1[r] * rl);
  }
}

// ---------------------------------------------------------------------------
// bf16 MFMA GEMM, C = A[M][K] @ BT[N][K]^T. BK=64 (2 k-chunks per barrier),
// XOR chunk swizzle (c ^= r&7) for conflict-free b128 frag reads, LDS-staged
// coalesced epilogue (dwordx4 stores). Split-K via blockIdx.z.
// ---------------------------------------------------------------------------
enum { MODE_QKV = 0, MODE_FF1 = 1, MODE_PART = 2 };

template <int MODE>
__global__ __launch_bounds__(256) void gemm_bt(
    const bf16_t* __restrict__ A, const bf16_t* __restrict__ BT,
    int M, int N, int K, int kspan,
    const float* __restrict__ bias0, const float* __restrict__ bias1,
    const float* __restrict__ bias2,
    bf16_t* __restrict__ ob0, bf16_t* __restrict__ ob1, bf16_t* __restrict__ ob2) {
  // loop phase: As 128x64 bf16 (16 KB) + Bs (16 KB); epilogue: 128x136 bf16 (34816 B)
  __shared__ __align__(16) char smem[34816];
  bf16_t* As = (bf16_t*)smem;
  bf16_t* Bs = (bf16_t*)(smem + 16384);
  const int tid = threadIdx.x;
  const int wave = tid >> 6, lane = tid & 63;
  const int row16 = lane & 15, quad = lane >> 4;
  const int m0 = blockIdx.x * 128, n0 = blockIdx.y * 128;
  const int wm = (wave & 1) << 6, wn = (wave >> 1) << 6;

  f32x4 acc[4][4];
#pragma unroll
  for (int i = 0; i < 4; ++i)
#pragma unroll
    for (int j = 0; j < 4; ++j) acc[i][j] = (f32x4){0.f, 0.f, 0.f, 0.f};

  const int kb = blockIdx.z * kspan;
  const int kend = (kb + kspan < K) ? kb + kspan : K;

  for (int k0 = kb; k0 < kend; k0 += 64) {
#pragma unroll
    for (int j = 0; j < 4; ++j) {
      const int s = j * 256 + tid;
      const int r = s >> 3;
      const int cg = ((s & 7) ^ (r & 7)) << 3;  // element offset of swizzled chunk
      gload_lds16(A + (size_t)(m0 + r) * K + k0 + cg, As + (size_t)s * 8);
      gload_lds16(BT + (size_t)(n0 + r) * K + k0 + cg, Bs + (size_t)s * 8);
    }
    __syncthreads();
    const int sw = row16 & 7;
#pragma unroll
    for (int kk = 0; kk < 2; ++kk) {
      short8 af[4], bfr[4];
#pragma unroll
      for (int mi = 0; mi < 4; ++mi)
        af[mi] = *(const short8*)&As[(size_t)(wm + mi * 16 + row16) * 64 + (((kk << 2) | quad) ^ sw) * 8];
#pragma unroll
      for (int ni = 0; ni < 4; ++ni)
        bfr[ni] = *(const short8*)&Bs[(size_t)(wn + ni * 16 + row16) * 64 + (((kk << 2) | quad) ^ sw) * 8];
#pragma unroll
      for (int mi = 0; mi < 4; ++mi)
#pragma unroll
        for (int ni = 0; ni < 4; ++ni)
          acc[mi][ni] =
              __builtin_amdgcn_mfma_f32_16x16x32_bf16(af[mi], bfr[ni], acc[mi][ni], 0, 0, 0);
    }
    __syncthreads();
  }

  // --- epilogue: bias/activation in regs -> bf16 tile in LDS -> coalesced stores
  bf16_t* ct = (bf16_t*)smem;  // [128][136]
#pragma unroll
  for (int mi = 0; mi < 4; ++mi)
#pragma unroll
    for (int ni = 0; ni < 4; ++ni) {
      const int gn = n0 + wn + ni * 16 + row16;
      float bsv = 0.f;
      if (MODE == MODE_QKV)
        bsv = (gn < 1024) ? bias0[gn] : (gn < 2048) ? bias1[gn - 1024] : bias2[gn - 2048];
      else if (MODE == MODE_FF1)
        bsv = bias0[gn];
#pragma unroll
      for (int r = 0; r < 4; ++r) {
        float c = acc[mi][ni][r] + bsv;
        if (MODE == MODE_FF1) c = fmaxf(c, 0.f);
        ct[(size_t)(wm + mi * 16 + quad * 4 + r) * 136 + wn + ni * 16 + row16] = f2bf(c);
      }
    }
  __syncthreads();
  const int lr0 = tid >> 4, lc = tid & 15;
#pragma unroll
  for (int i = 0; i < 8; ++i) {
    const int lr = i * 16 + lr0;
    const uint4 v = *(const uint4*)&ct[(size_t)lr * 136 + lc * 8];
    const int gm = m0 + lr;
    if (MODE == MODE_QKV) {
      const int nn = (n0 & 1023) + lc * 8;
      const int h = nn >> 6, d = nn & 63;
      const int b = gm >> 11, s = gm & 2047;
      bf16_t* dst = (n0 < 1024) ? ob0 : (n0 < 2048) ? ob1 : ob2;
      *(uint4*)&dst[(((size_t)b * 16 + h) * 2048 + s) * 64 + d] = v;
    } else if (MODE == MODE_FF1) {
      *(uint4*)&ob0[(size_t)gm * N + n0 + lc * 8] = v;
    } else {  // MODE_PART
      bf16_t* dst = (blockIdx.z == 2) ? ob1 : ob0 + (size_t)blockIdx.z * 4194304;
      *(uint4*)&dst[(size_t)gm * N + n0 + lc * 8] = v;
    }
  }
}

// ---------------------------------------------------------------------------
extern "C" void kernel_launch(void* const* d_in, const int* in_sizes, int n_in,
                              void* d_out, int out_size, void* d_ws, size_t ws_size,
                              hipStream_t stream) {
  const float* x = (const float*)d_in[0];
  const float* Wq = (const float*)d_in[1];
  const float* bq = (const float*)d_in[2];
  const float* Wk = (const float*)d_in[3];
  const float* bk = (const float*)d_in[4];
  const float* Wv = (const float*)d_in[5];
  const float* bv = (const float*)d_in[6];
  const float* Wo = (const float*)d_in[7];
  const float* bo = (const float*)d_in[8];
  const float* W1 = (const float*)d_in[9];
  const float* b1 = (const float*)d_in[10];
  const float* W2 = (const float*)d_in[11];
  const float* b2 = (const float*)d_in[12];
  const float* g1 = (const float*)d_in[13];
  const float* be1 = (const float*)d_in[14];
  const float* g2 = (const float*)d_in[15];
  const float* be2 = (const float*)d_in[16];
  float* out = (float*)d_out;

  char* ws = (char*)d_ws;
  size_t off = 0;
  auto alloc = [&](size_t bytes) {
    void* p = ws + off;
    off += (bytes + 255) & ~(size_t)255;
    return p;
  };
  bf16_t* WqkvT = (bf16_t*)alloc(3072ULL * 1024 * 2);  // [0,6MB)
  bf16_t* WoT = (bf16_t*)alloc(1024ULL * 1024 * 2);    // [6,8)
  bf16_t* W1T = (bf16_t*)alloc(4096ULL * 1024 * 2);    // [8,16)
  bf16_t* W2T = (bf16_t*)alloc(1024ULL * 4096 * 2);    // [16,24)
  bf16_t* xnb = (bf16_t*)alloc(4096ULL * 1024 * 2);    // [24,32) xn1/attn_out/xn2/FF2-partial2
  bf16_t* qb = (bf16_t*)alloc(4194304ULL * 2);         // [32,40)
  bf16_t* kb = (bf16_t*)alloc(4194304ULL * 2);         // [40,48)
  bf16_t* vraw = (bf16_t*)alloc(4194304ULL * 2);       // [48,56) V [b,h,s,d]
  bf16_t* vt = (bf16_t*)alloc(4194304ULL * 2);         // [56,64) V^T [b,h,d,s]
  bf16_t* h1 = qb;       // FF1 out [4096][4096] bf16 over [32,64)
  bf16_t* x2p = qb;      // X2 bf16 partials (4 x 8MB) over [32,64), pre-FF1
  bf16_t* ffp = WqkvT;   // FF2 partials 0,1 over dead weights [0,16)
  float* x2 = (float*)alloc(16777216ULL);              // [64,80)

  prep_kernel<<<16384, 256, 0, stream>>>(Wq, Wk, Wv, Wo, W1, W2, x, g1, be1,
                                         WqkvT, W1T, W2T, xnb);

  gemm_bt<MODE_QKV><<<dim3(32, 24, 1), 256, 0, stream>>>(xnb, WqkvT, 4096, 3072, 1024, 1024,
                                                         bq, bk, bv, qb, kb, vraw);

  rope_bf16<<<8192, 256, 0, stream>>>(qb, kb);

  vtrans<<<dim3(32, 64, 2), 256, 0, stream>>>(vraw, vt);

  attn6<<<dim3(32, 16), 256, 0, stream>>>(qb, kb, vt, xnb);

  // X2 = attn_out @ Wo, split-K=4 (kspan 256)
  gemm_bt<MODE_PART><<<dim3(32, 8, 4), 256, 0, stream>>>(xnb, WoT, 4096, 1024, 1024, 256,
                                                         nullptr, nullptr, nullptr,
                                                         x2p, x2p + 2 * 4194304, nullptr);

  ln2_combine<<<4096, 256, 0, stream>>>(x2p, x, bo, g2, be2, x2, xnb);

  gemm_bt<MODE_FF1><<<dim3(32, 32, 1), 256, 0, stream>>>(xnb, W1T, 4096, 4096, 1024, 1024,
                                                         b1, nullptr, nullptr,
                                                         h1, nullptr, nullptr);

  // FF2 = h1 @ W2, split-K=3 (1408/1408/1280; 64-multiples for BK=64)
  gemm_bt<MODE_PART><<<dim3(32, 8, 3), 256, 0, stream>>>(h1, W2T, 4096, 1024, 4096, 1408,
                                                         nullptr, nullptr, nullptr,
                                                         ffp, xnb, nullptr);

  ffn_combine<<<4096, 256, 0, stream>>>(ffp, xnb, x2, b2, out);
}

// Round 6
// 344.718 us; speedup vs baseline: 1.1048x; 1.0579x over previous
//
#include <hip/hip_runtime.h>

typedef unsigned short bf16_t;
typedef short short8 __attribute__((ext_vector_type(8)));
typedef float f32x4 __attribute__((ext_vector_type(4)));
typedef float f32x16 __attribute__((ext_vector_type(16)));
typedef unsigned int u32x4 __attribute__((ext_vector_type(4)));

extern "C" __device__ float __ocml_native_exp2_f32(float);

static __device__ __forceinline__ unsigned short f2bf(float f) {
  unsigned int u = __float_as_uint(f);
  unsigned int r = (u + 0x7FFFu + ((u >> 16) & 1u)) >> 16;
  return (unsigned short)r;
}
static __device__ __forceinline__ float bf2f(unsigned short u) {
  return __uint_as_float((unsigned int)u << 16);
}
static __device__ __forceinline__ unsigned int cvt_pk_bf16(float lo, float hi) {
  unsigned int r;
  asm("v_cvt_pk_bf16_f32 %0, %1, %2" : "=v"(r) : "v"(lo), "v"(hi));
  return r;
}
static __device__ __forceinline__ void pl32swap(unsigned int& a, unsigned int& b) {
  asm("v_permlane32_swap_b32 %0, %1" : "+v"(a), "+v"(b));
}

__device__ __forceinline__ void gload_lds16(const void* g, void* l) {
  __builtin_amdgcn_global_load_lds((const __attribute__((address_space(1))) void*)g,
                                   (__attribute__((address_space(3))) void*)l,
                                   16, 0, 0);
}

// ---------------------------------------------------------------------------
// Fused prep: blocks [0,4096) transpose Wq/Wk/Wv/Wo (1024x1024 each);
// [4096,8192) W1 (1024x4096); [8192,12288) W2 (4096x1024);
// [12288,16384) LayerNorm rows of x.
// ---------------------------------------------------------------------------
__global__ __launch_bounds__(256) void prep_kernel(
    const float* __restrict__ Wq, const float* __restrict__ Wk,
    const float* __restrict__ Wv, const float* __restrict__ Wo,
    const float* __restrict__ W1, const float* __restrict__ W2,
    const float* __restrict__ x, const float* __restrict__ g1,
    const float* __restrict__ be1,
    bf16_t* __restrict__ WqkvT, bf16_t* __restrict__ W1T,
    bf16_t* __restrict__ W2T, bf16_t* __restrict__ xnb) {
  __shared__ float tile[32][33];
  const int bid = blockIdx.x;
  if (bid < 12288) {
    const float* src;
    bf16_t* dst;
    int rows, cols, bx, by;
    if (bid < 4096) {
      const int z = bid >> 10, r = bid & 1023;
      src = (z == 0) ? Wq : (z == 1) ? Wk : (z == 2) ? Wv : Wo;
      dst = WqkvT + (size_t)z * 1048576;
      rows = 1024; cols = 1024;
      bx = (r & 31) * 32; by = (r >> 5) * 32;
    } else if (bid < 8192) {
      const int r = bid - 4096;
      src = W1; dst = W1T; rows = 1024; cols = 4096;
      bx = (r & 127) * 32; by = (r >> 7) * 32;
    } else {
      const int r = bid - 8192;
      src = W2; dst = W2T; rows = 4096; cols = 1024;
      bx = (r & 31) * 32; by = (r >> 5) * 32;
    }
    const int tx = threadIdx.x & 31, ty = threadIdx.x >> 5;
#pragma unroll
    for (int i = 0; i < 32; i += 8)
      tile[ty + i][tx] = src[(size_t)(by + ty + i) * cols + (bx + tx)];
    __syncthreads();
#pragma unroll
    for (int i = 0; i < 32; i += 8)
      dst[(size_t)(bx + ty + i) * rows + (by + tx)] = f2bf(tile[tx][ty + i]);
  } else {
    const int row = bid - 12288;
    const int tid = threadIdx.x;
    const float4 v = reinterpret_cast<const float4*>(x + (size_t)row * 1024)[tid];
    float s = v.x + v.y + v.z + v.w;
    float ss = v.x * v.x + v.y * v.y + v.z * v.z + v.w * v.w;
#pragma unroll
    for (int off = 32; off; off >>= 1) {
      s += __shfl_xor(s, off, 64);
      ss += __shfl_xor(ss, off, 64);
    }
    float* red = &tile[0][0];
    const int wave = tid >> 6, lane = tid & 63;
    if (lane == 0) { red[wave] = s; red[4 + wave] = ss; }
    __syncthreads();
    const float mu = (red[0] + red[1] + red[2] + red[3]) * (1.f / 1024.f);
    const float ms = (red[4] + red[5] + red[6] + red[7]) * (1.f / 1024.f);
    const float rstd = rsqrtf(ms - mu * mu + 1e-5f);
    const float4 gg = reinterpret_cast<const float4*>(g1)[tid];
    const float4 bb = reinterpret_cast<const float4*>(be1)[tid];
    bf16_t* o = xnb + (size_t)row * 1024 + tid * 4;
    o[0] = f2bf((v.x - mu) * rstd * gg.x + bb.x);
    o[1] = f2bf((v.y - mu) * rstd * gg.y + bb.y);
    o[2] = f2bf((v.z - mu) * rstd * gg.z + bb.z);
    o[3] = f2bf((v.w - mu) * rstd * gg.w + bb.w);
  }
}

// ---------------------------------------------------------------------------
// LN2-combine: x2 = sum(4 bf16 partials)+bo+x ; x2 f32 out + xn2 = LN(x2) bf16
// ---------------------------------------------------------------------------
__global__ __launch_bounds__(256) void ln2_combine(const bf16_t* __restrict__ p,
                                                   const float* __restrict__ x,
                                                   const float* __restrict__ bo,
                                                   const float* __restrict__ g,
                                                   const float* __restrict__ be,
                                                   float* __restrict__ x2,
                                                   bf16_t* __restrict__ xn) {
  const int row = blockIdx.x;
  const int tid = threadIdx.x;
  const float4 xv = reinterpret_cast<const float4*>(x + (size_t)row * 1024)[tid];
  const float4 bb = reinterpret_cast<const float4*>(bo)[tid];
  float4 v = {bb.x + xv.x, bb.y + xv.y, bb.z + xv.z, bb.w + xv.w};
#pragma unroll
  for (int z = 0; z < 4; ++z) {
    const ushort4 a = reinterpret_cast<const ushort4*>(p + (size_t)z * 4194304 + (size_t)row * 1024)[tid];
    v.x += bf2f(a.x); v.y += bf2f(a.y); v.z += bf2f(a.z); v.w += bf2f(a.w);
  }
  reinterpret_cast<float4*>(x2 + (size_t)row * 1024)[tid] = v;
  float s = v.x + v.y + v.z + v.w;
  float ss = v.x * v.x + v.y * v.y + v.z * v.z + v.w * v.w;
#pragma unroll
  for (int off = 32; off; off >>= 1) {
    s += __shfl_xor(s, off, 64);
    ss += __shfl_xor(ss, off, 64);
  }
  __shared__ float red[8];
  const int wave = tid >> 6, lane = tid & 63;
  if (lane == 0) { red[wave] = s; red[4 + wave] = ss; }
  __syncthreads();
  const float mu = (red[0] + red[1] + red[2] + red[3]) * (1.f / 1024.f);
  const float ms = (red[4] + red[5] + red[6] + red[7]) * (1.f / 1024.f);
  const float rstd = rsqrtf(ms - mu * mu + 1e-5f);
  const float4 gg = reinterpret_cast<const float4*>(g)[tid];
  const float4 eb = reinterpret_cast<const float4*>(be)[tid];
  bf16_t* o = xn + (size_t)row * 1024 + tid * 4;
  o[0] = f2bf((v.x - mu) * rstd * gg.x + eb.x);
  o[1] = f2bf((v.y - mu) * rstd * gg.y + eb.y);
  o[2] = f2bf((v.z - mu) * rstd * gg.z + eb.z);
  o[3] = f2bf((v.w - mu) * rstd * gg.w + eb.w);
}

// ---------------------------------------------------------------------------
// FFN combine: out = bf(p0)+bf(p1)+bf(p2)+b2+x2
// ---------------------------------------------------------------------------
__global__ __launch_bounds__(256) void ffn_combine(const bf16_t* __restrict__ p0,
                                                   const bf16_t* __restrict__ p2,
                                                   const float* __restrict__ x2,
                                                   const float* __restrict__ b2,
                                                   float* __restrict__ out) {
  const int row = blockIdx.x;
  const int tid = threadIdx.x;
  const ushort4 a0 = reinterpret_cast<const ushort4*>(p0 + (size_t)row * 1024)[tid];
  const ushort4 a1 = reinterpret_cast<const ushort4*>(p0 + 4194304 + (size_t)row * 1024)[tid];
  const ushort4 a2 = reinterpret_cast<const ushort4*>(p2 + (size_t)row * 1024)[tid];
  const float4 xv = reinterpret_cast<const float4*>(x2 + (size_t)row * 1024)[tid];
  const float4 bb = reinterpret_cast<const float4*>(b2)[tid];
  float4 v;
  v.x = bf2f(a0.x) + bf2f(a1.x) + bf2f(a2.x) + bb.x + xv.x;
  v.y = bf2f(a0.y) + bf2f(a1.y) + bf2f(a2.y) + bb.y + xv.y;
  v.z = bf2f(a0.z) + bf2f(a1.z) + bf2f(a2.z) + bb.z + xv.z;
  v.w = bf2f(a0.w) + bf2f(a1.w) + bf2f(a2.w) + bb.w + xv.w;
  reinterpret_cast<float4*>(out + (size_t)row * 1024)[tid] = v;
}

// ---------------------------------------------------------------------------
// RoPE in place on bf16 q,k [B,H,S,64]; q scaled by (1/8)*log2(e).
// ---------------------------------------------------------------------------
__global__ __launch_bounds__(256) void rope_bf16(bf16_t* __restrict__ q,
                                                 bf16_t* __restrict__ k) {
  const int id = blockIdx.x * 256 + threadIdx.x;
  const int i = id & 31;
  const int s = (id >> 5) & 2047;
  const int bh = id >> 16;
  const float inv = exp2f((float)i * -0.41524101186f);
  float sn, cs;
  sincosf((float)s * inv, &sn, &cs);
  const size_t base = ((size_t)bh * 2048 + s) * 64 + 2 * i;
  unsigned int qp = *(unsigned int*)&q[base];
  unsigned int kp = *(unsigned int*)&k[base];
  const float q0 = bf2f(qp & 0xffff), q1 = bf2f(qp >> 16);
  const float k0 = bf2f(kp & 0xffff), k1 = bf2f(kp >> 16);
  const float qs = 0.18033688f;  // 0.125 * log2(e)
  const unsigned int qo =
      (unsigned int)f2bf((q0 * cs - q1 * sn) * qs) |
      ((unsigned int)f2bf((q0 * sn + q1 * cs) * qs) << 16);
  const unsigned int ko =
      (unsigned int)f2bf(k0 * cs - k1 * sn) |
      ((unsigned int)f2bf(k0 * sn + k1 * cs) << 16);
  *(unsigned int*)&q[base] = qo;
  *(unsigned int*)&k[base] = ko;
}

// ---------------------------------------------------------------------------
// V transpose: v [b,h,s,64] bf16 -> vt [b,h,64,2048] bf16
// ---------------------------------------------------------------------------
__global__ __launch_bounds__(256) void vtrans(const bf16_t* __restrict__ v,
                                              bf16_t* __restrict__ vt) {
  __shared__ bf16_t tile[32][33];
  const int bh = blockIdx.x;
  const int s0 = blockIdx.y * 32;
  const int d0 = blockIdx.z * 32;
  const int tx = threadIdx.x & 31, ty = threadIdx.x >> 5;
  const size_t base = (size_t)bh * (2048 * 64);
#pragma unroll
  for (int i = 0; i < 32; i += 8)
    tile[ty + i][tx] = v[base + (size_t)(s0 + ty + i) * 64 + d0 + tx];
  __syncthreads();
#pragma unroll
  for (int i = 0; i < 32; i += 8)
    vt[base + (size_t)(d0 + ty + i) * 2048 + s0 + tx] = tile[tx][ty + i];
}

// ---------------------------------------------------------------------------
// attn7: attn6 + native v_exp_f32 (replaces exp2f libcall fixup code).
// ---------------------------------------------------------------------------
__global__ __launch_bounds__(256, 2) void attn7(const bf16_t* __restrict__ qb,
                                                const bf16_t* __restrict__ kb,
                                                const bf16_t* __restrict__ vt,
                                                bf16_t* __restrict__ out) {
  const int bh = blockIdx.x;
  const int tid = threadIdx.x, wave = tid >> 6, lane = tid & 63;
  const int l31 = lane & 31, hi = lane >> 5;
  const int q0 = blockIdx.y * 128 + wave * 32;
  const size_t kvb = (size_t)bh * (2048 * 64);

  __shared__ __align__(16) bf16_t Ks[2][2][4096];
  __shared__ __align__(16) bf16_t Vs[2][2][4096];

  short8 qf[4];
#pragma unroll
  for (int st = 0; st < 4; ++st)
    qf[st] = *(const short8*)&qb[kvb + (size_t)(q0 + l31) * 64 + st * 16 + hi * 8];

  int kidx[2][4];
  int vidx[2][2][2];
#pragma unroll
  for (int st = 0; st < 4; ++st) {
    const int R0 = l31, R1 = 32 + l31;
    kidx[0][st] = (R0 * 8 + (((st << 1) | hi) ^ (R0 & 7))) * 8;
    kidx[1][st] = (R1 * 8 + (((st << 1) | hi) ^ (R1 & 7))) * 8;
  }
#pragma unroll
  for (int f = 0; f < 2; ++f)
#pragma unroll
    for (int ks = 0; ks < 2; ++ks) {
      const int R0 = l31, R1 = 32 + l31;
      vidx[0][f][ks] = (R0 * 8 + (((f << 2) | (ks << 1) | hi) ^ (R0 & 7))) * 8;
      vidx[1][f][ks] = (R1 * 8 + (((f << 2) | (ks << 1) | hi) ^ (R1 & 7))) * 8;
    }

  short8 vones;
#pragma unroll
  for (int j = 0; j < 8; ++j) vones[j] = (short)0x3F80;

  f32x16 acc0 = {}, acc1 = {}, lacc = {};
  const f32x16 fz = {};

#define STAGE(DST, T0)                                                                     \
  {                                                                                        \
    _Pragma("unroll") for (int sub = 0; sub < 2; ++sub) {                                  \
      _Pragma("unroll") for (int j = 0; j < 2; ++j) {                                      \
        const int s = wave * 128 + j * 64 + lane;                                          \
        const int r = s >> 3;                                                              \
        const int c = (s & 7) ^ (r & 7);                                                   \
        gload_lds16(kb + kvb + (size_t)((T0) + sub * 64 + r) * 64 + c * 8,                 \
                    &Ks[DST][sub][(size_t)s * 8]);                                         \
        gload_lds16(vt + kvb + (size_t)r * 2048 + (T0) + sub * 64 + c * 8,                 \
                    &Vs[DST][sub][(size_t)s * 8]);                                         \
      }                                                                                    \
    }                                                                                      \
  }

#define QK(BUF, SUB, P0, P1)                                                               \
  {                                                                                        \
    short8 kfa[4], kfb[4];                                                                 \
    _Pragma("unroll") for (int st = 0; st < 4; ++st) {                                     \
      kfa[st] = *(const short8*)&Ks[BUF][SUB][kidx[0][st]];                                \
      kfb[st] = *(const short8*)&Ks[BUF][SUB][kidx[1][st]];                                \
    }                                                                                      \
    __builtin_amdgcn_s_setprio(1);                                                         \
    P0 = __builtin_amdgcn_mfma_f32_32x32x16_bf16(kfa[0], qf[0], fz, 0, 0, 0);              \
    P1 = __builtin_amdgcn_mfma_f32_32x32x16_bf16(kfb[0], qf[0], fz, 0, 0, 0);              \
    _Pragma("unroll") for (int st = 1; st < 4; ++st) {                                     \
      P0 = __builtin_amdgcn_mfma_f32_32x32x16_bf16(kfa[st], qf[st], P0, 0, 0, 0);          \
      P1 = __builtin_amdgcn_mfma_f32_32x32x16_bf16(kfb[st], qf[st], P1, 0, 0, 0);          \
    }                                                                                      \
    __builtin_amdgcn_s_setprio(0);                                                         \
  }

#define SMPV(BUF, SUB, P0, P1)                                                             \
  {                                                                                        \
    _Pragma("unroll") for (int f = 0; f < 2; ++f) {                                        \
      f32x16& p = f ? P1 : P0;                                                             \
      float e[16];                                                                         \
      _Pragma("unroll") for (int r = 0; r < 16; ++r) e[r] = __ocml_native_exp2_f32(p[r]);  \
      unsigned int a0 = cvt_pk_bf16(e[0], e[1]), b0 = cvt_pk_bf16(e[4], e[5]);             \
      unsigned int a1 = cvt_pk_bf16(e[2], e[3]), b1 = cvt_pk_bf16(e[6], e[7]);             \
      unsigned int a2 = cvt_pk_bf16(e[8], e[9]), b2 = cvt_pk_bf16(e[12], e[13]);           \
      unsigned int a3 = cvt_pk_bf16(e[10], e[11]), b3 = cvt_pk_bf16(e[14], e[15]);         \
      pl32swap(a0, b0);                                                                    \
      pl32swap(a1, b1);                                                                    \
      pl32swap(a2, b2);                                                                    \
      pl32swap(a3, b3);                                                                    \
      const u32x4 w0 = {a0, a1, b0, b1};                                                   \
      const u32x4 w1 = {a2, a3, b2, b3};                                                   \
      const short8 pf0 = __builtin_bit_cast(short8, w0);                                   \
      const short8 pf1 = __builtin_bit_cast(short8, w1);                                   \
      const short8 vf00 = *(const short8*)&Vs[BUF][SUB][vidx[0][f][0]];                    \
      const short8 vf10 = *(const short8*)&Vs[BUF][SUB][vidx[1][f][0]];                    \
      const short8 vf01 = *(const short8*)&Vs[BUF][SUB][vidx[0][f][1]];                    \
      const short8 vf11 = *(const short8*)&Vs[BUF][SUB][vidx[1][f][1]];                    \
      __builtin_amdgcn_s_setprio(1);                                                       \
      lacc = __builtin_amdgcn_mfma_f32_32x32x16_bf16(pf0, vones, lacc, 0, 0, 0);           \
      acc0 = __builtin_amdgcn_mfma_f32_32x32x16_bf16(pf0, vf00, acc0, 0, 0, 0);            \
      acc1 = __builtin_amdgcn_mfma_f32_32x32x16_bf16(pf0, vf10, acc1, 0, 0, 0);            \
      lacc = __builtin_amdgcn_mfma_f32_32x32x16_bf16(pf1, vones, lacc, 0, 0, 0);           \
      acc0 = __builtin_amdgcn_mfma_f32_32x32x16_bf16(pf1, vf01, acc0, 0, 0, 0);            \
      acc1 = __builtin_amdgcn_mfma_f32_32x32x16_bf16(pf1, vf11, acc1, 0, 0, 0);            \
      __builtin_amdgcn_s_setprio(0);                                                       \
    }                                                                                      \
  }

#define CITER(BUF, NT0, DOPREF)                                                            \
  {                                                                                        \
    if (DOPREF) {                                                                          \
      STAGE((BUF) ^ 1, NT0);                                                               \
      asm volatile("s_waitcnt vmcnt(8)" ::: "memory");                                     \
    } else {                                                                               \
      asm volatile("s_waitcnt vmcnt(0)" ::: "memory");                                     \
    }                                                                                      \
    __builtin_amdgcn_s_barrier();                                                          \
    asm volatile("" ::: "memory");                                                         \
    f32x16 pa0, pa1, pb0, pb1;                                                             \
    QK(BUF, 0, pa0, pa1);                                                                  \
    QK(BUF, 1, pb0, pb1);                                                                  \
    SMPV(BUF, 0, pa0, pa1);                                                                \
    SMPV(BUF, 1, pb0, pb1);                                                                \
    asm volatile("" ::: "memory");                                                         \
    __builtin_amdgcn_s_barrier();                                                          \
    asm volatile("" ::: "memory");                                                         \
  }

  STAGE(0, 0);

  for (int k = 0; k < 7; ++k) {
    CITER(0, (2 * k + 1) * 128, 1)
    CITER(1, (2 * k + 2) * 128, 1)
  }
  CITER(0, 1920, 1)
  CITER(1, 0, 0)
#undef CITER
#undef SMPV
#undef QK
#undef STAGE

  const int b = bh >> 4, h = bh & 15;
#pragma unroll
  for (int r = 0; r < 16; ++r) {
    const int qrow = (r & 3) + 8 * (r >> 2) + 4 * hi;
    const float rl = 1.f / lacc[r];
    const size_t ro = (size_t)(b * 2048 + q0 + qrow) * 1024 + h * 64;
    out[ro + l31] = f2bf(acc0[r] * rl);
    out[ro + 32 + l31] = f2bf(acc1[r] * rl);
  }
}

// ---------------------------------------------------------------------------
// gemm_ff1_256: 256x256-tile 8-wave 8-phase counted-vmcnt bf16 GEMM for
// FF1: h1 = relu(xnb[4096][1024] @ W1T[4096][1024]^T + b1), bf16 out.
// LDS = 2 slots x {Ak0,Ak1,Bk0,Bk1} halves (256 rows x 32 k each, 16KB).
// Per K-tile: 4 phases {stage 1 half, ds_read frags, [vmcnt], barrier,
// 16 MFMA (setprio), barrier}. Stage order: Bk0(t+1)@p1, Ak1(t+1)@p2,
// Bk1(t+1)@p3, Ak0(t+2)@p4 (into current slot - its Ak0 died at p2).
// vmcnt(6)@p2 / vmcnt(4)@p4 guarantee 3-halves-back landed after barrier.
// ---------------------------------------------------------------------------
#define SWZ4(r) (((r) ^ ((r) >> 2)) & 3)
#define HP(SL, H) (dynlds + (size_t)(((SL) * 4 + (H)) * 8192))

#define STAGE8(dst, src, row0, kc0)                                             \
  {                                                                             \
    _Pragma("unroll") for (int j = 0; j < 2; ++j) {                             \
      const int s_ = j * 512 + tid;                                             \
      const int r_ = s_ >> 2;                                                   \
      const int c_ = (s_ & 3) ^ SWZ4(r_);                                       \
      gload_lds16(src + (size_t)((row0) + r_) * 1024 + (kc0) + c_ * 8,          \
                  (dst) + (size_t)s_ * 8);                                      \
    }                                                                           \
  }

#define PHASE(SL, KH, MH, STG, VMW)                                             \
  {                                                                             \
    STG;                                                                        \
    short8 af_[4];                                                              \
    _Pragma("unroll") for (int q4 = 0; q4 < 4; ++q4)                            \
      af_[q4] = *(const short8*)(HP(SL, KH) + aidx[(MH) * 4 + q4]);             \
    if ((MH) == 0) {                                                            \
      _Pragma("unroll") for (int ni = 0; ni < 4; ++ni)                          \
        bfr[ni] = *(const short8*)(HP(SL, 2 + (KH)) + bidx[ni]);                \
    }                                                                           \
    VMW;                                                                        \
    asm volatile("" ::: "memory");                                              \
    __builtin_amdgcn_s_barrier();                                               \
    asm volatile("" ::: "memory");                                              \
    __builtin_amdgcn_s_setprio(1);                                              \
    _Pragma("unroll") for (int q4 = 0; q4 < 4; ++q4)                            \
      _Pragma("unroll") for (int ni = 0; ni < 4; ++ni)                          \
        acc[(MH) * 4 + q4][ni] = __builtin_amdgcn_mfma_f32_16x16x32_bf16(       \
            af_[q4], bfr[ni], acc[(MH) * 4 + q4][ni], 0, 0, 0);                 \
    __builtin_amdgcn_s_setprio(0);                                              \
    asm volatile("" ::: "memory");                                              \
    __builtin_amdgcn_s_barrier();                                               \
    asm volatile("" ::: "memory");                                              \
  }

#define KTILE(SL, KT, VM2, VM4)                                                 \
  PHASE(SL, 0, 0,                                                               \
        if ((KT) + 1 < 16) STAGE8(HP((SL) ^ 1, 2), BT, n0, ((KT) + 1) * 64),    \
        (void)0)                                                                \
  PHASE(SL, 0, 1,                                                               \
        if ((KT) + 1 < 16) STAGE8(HP((SL) ^ 1, 1), A, m0, ((KT) + 1) * 64 + 32),\
        asm volatile("s_waitcnt vmcnt(" #VM2 ")" ::: "memory"))                 \
  PHASE(SL, 1, 0,                                                               \
        if ((KT) + 1 < 16) STAGE8(HP((SL) ^ 1, 3), BT, n0, ((KT) + 1) * 64 + 32),\
        (void)0)                                                                \
  PHASE(SL, 1, 1,                                                               \
        if ((KT) + 2 < 16) STAGE8(HP(SL, 0), A, m0, ((KT) + 2) * 64),           \
        asm volatile("s_waitcnt vmcnt(" #VM4 ")" ::: "memory"))

__global__ __launch_bounds__(512, 2) void gemm_ff1_256(
    const bf16_t* __restrict__ A, const bf16_t* __restrict__ BT,
    const float* __restrict__ bias, bf16_t* __restrict__ ob) {
  extern __shared__ bf16_t dynlds[];
  const int tid = threadIdx.x;
  const int wave = tid >> 6, lane = tid & 63;
  const int row16 = lane & 15, quad = lane >> 4;
  const int wr = wave >> 2, wc = wave & 3;
  const int m0 = blockIdx.x * 256, n0 = blockIdx.y * 256;

  int aidx[8], bidx[4];
#pragma unroll
  for (int mi = 0; mi < 8; ++mi) {
    const int R = wr * 128 + mi * 16 + row16;
    aidx[mi] = R * 32 + (quad ^ SWZ4(R)) * 8;
  }
#pragma unroll
  for (int ni = 0; ni < 4; ++ni) {
    const int R = wc * 64 + ni * 16 + row16;
    bidx[ni] = R * 32 + (quad ^ SWZ4(R)) * 8;
  }

  f32x4 acc[8][4];
#pragma unroll
  for (int i = 0; i < 8; ++i)
#pragma unroll
    for (int j = 0; j < 4; ++j) acc[i][j] = (f32x4){0.f, 0.f, 0.f, 0.f};
  short8 bfr[4];

  // prologue: K-tile 0 fully + Ak0 of K-tile 1; full drain via syncthreads.
  STAGE8(HP(0, 0), A, m0, 0);
  STAGE8(HP(0, 2), BT, n0, 0);
  STAGE8(HP(0, 1), A, m0, 32);
  STAGE8(HP(0, 3), BT, n0, 32);
  STAGE8(HP(1, 0), A, m0, 64);
  __syncthreads();

  for (int kt2 = 0; kt2 < 7; ++kt2) {
    const int kt = 2 * kt2;
    KTILE(0, kt, 6, 4)
    KTILE(1, kt + 1, 6, 4)
  }
  KTILE(0, 14, 6, 4)
  KTILE(1, 15, 0, 0)

  // epilogue: 2-pass LDS-staged coalesced stores with bias+relu.
  __syncthreads();
  bf16_t* ct = dynlds;  // [128][264]
  float bsv[4];
#pragma unroll
  for (int ni = 0; ni < 4; ++ni) bsv[ni] = bias[n0 + wc * 64 + ni * 16 + row16];
#pragma unroll
  for (int mh = 0; mh < 2; ++mh) {
    if (wr == mh) {
#pragma unroll
      for (int mi = 0; mi < 8; ++mi)
#pragma unroll
        for (int ni = 0; ni < 4; ++ni)
#pragma unroll
          for (int r = 0; r < 4; ++r) {
            const float c = fmaxf(acc[mi][ni][r] + bsv[ni], 0.f);
            ct[(size_t)(mi * 16 + quad * 4 + r) * 264 + wc * 64 + ni * 16 + row16] = f2bf(c);
          }
    }
    __syncthreads();
#pragma unroll
    for (int it = 0; it < 8; ++it) {
      const int u = it * 512 + tid;
      const int lr = u >> 5, lcq = u & 31;
      const uint4 v = *(const uint4*)&ct[(size_t)lr * 264 + lcq * 8];
      *(uint4*)&ob[(size_t)(m0 + mh * 128 + lr) * 4096 + n0 + lcq * 8] = v;
    }
    __syncthreads();
  }
}

// ---------------------------------------------------------------------------
// bf16 MFMA GEMM, C = A[M][K] @ BT[N][K]^T (m97-class; QKV/Wo/FF2).
// ---------------------------------------------------------------------------
enum { MODE_QKV = 0, MODE_FF1 = 1, MODE_PART = 2 };

template <int MODE>
__global__ __launch_bounds__(256) void gemm_bt(
    const bf16_t* __restrict__ A, const bf16_t* __restrict__ BT,
    int M, int N, int K, int kspan,
    const float* __restrict__ bias0, const float* __restrict__ bias1,
    const float* __restrict__ bias2,
    bf16_t* __restrict__ ob0, bf16_t* __restrict__ ob1, bf16_t* __restrict__ ob2) {
  __shared__ __align__(16) char smem[34816];
  bf16_t* As = (bf16_t*)smem;
  bf16_t* Bs = (bf16_t*)(smem + 16384);
  const int tid = threadIdx.x;
  const int wave = tid >> 6, lane = tid & 63;
  const int row16 = lane & 15, quad = lane >> 4;
  const int m0 = blockIdx.x * 128, n0 = blockIdx.y * 128;
  const int wm = (wave & 1) << 6, wn = (wave >> 1) << 6;

  f32x4 acc[4][4];
#pragma unroll
  for (int i = 0; i < 4; ++i)
#pragma unroll
    for (int j = 0; j < 4; ++j) acc[i][j] = (f32x4){0.f, 0.f, 0.f, 0.f};

  const int kb = blockIdx.z * kspan;
  const int kend = (kb + kspan < K) ? kb + kspan : K;

  for (int k0 = kb; k0 < kend; k0 += 64) {
#pragma unroll
    for (int j = 0; j < 4; ++j) {
      const int s = j * 256 + tid;
      const int r = s >> 3;
      const int cg = ((s & 7) ^ (r & 7)) << 3;
      gload_lds16(A + (size_t)(m0 + r) * K + k0 + cg, As + (size_t)s * 8);
      gload_lds16(BT + (size_t)(n0 + r) * K + k0 + cg, Bs + (size_t)s * 8);
    }
    __syncthreads();
    const int sw = row16 & 7;
#pragma unroll
    for (int kk = 0; kk < 2; ++kk) {
      short8 af[4], bfr[4];
#pragma unroll
      for (int mi = 0; mi < 4; ++mi)
        af[mi] = *(const short8*)&As[(size_t)(wm + mi * 16 + row16) * 64 + (((kk << 2) | quad) ^ sw) * 8];
#pragma unroll
      for (int ni = 0; ni < 4; ++ni)
        bfr[ni] = *(const short8*)&Bs[(size_t)(wn + ni * 16 + row16) * 64 + (((kk << 2) | quad) ^ sw) * 8];
#pragma unroll
      for (int mi = 0; mi < 4; ++mi)
#pragma unroll
        for (int ni = 0; ni < 4; ++ni)
          acc[mi][ni] =
              __builtin_amdgcn_mfma_f32_16x16x32_bf16(af[mi], bfr[ni], acc[mi][ni], 0, 0, 0);
    }
    __syncthreads();
  }

  bf16_t* ct = (bf16_t*)smem;  // [128][136]
#pragma unroll
  for (int mi = 0; mi < 4; ++mi)
#pragma unroll
    for (int ni = 0; ni < 4; ++ni) {
      const int gn = n0 + wn + ni * 16 + row16;
      float bsv = 0.f;
      if (MODE == MODE_QKV)
        bsv = (gn < 1024) ? bias0[gn] : (gn < 2048) ? bias1[gn - 1024] : bias2[gn - 2048];
      else if (MODE == MODE_FF1)
        bsv = bias0[gn];
#pragma unroll
      for (int r = 0; r < 4; ++r) {
        float c = acc[mi][ni][r] + bsv;
        if (MODE == MODE_FF1) c = fmaxf(c, 0.f);
        ct[(size_t)(wm + mi * 16 + quad * 4 + r) * 136 + wn + ni * 16 + row16] = f2bf(c);
      }
    }
  __syncthreads();
  const int lr0 = tid >> 4, lc = tid & 15;
#pragma unroll
  for (int i = 0; i < 8; ++i) {
    const int lr = i * 16 + lr0;
    const uint4 v = *(const uint4*)&ct[(size_t)lr * 136 + lc * 8];
    const int gm = m0 + lr;
    if (MODE == MODE_QKV) {
      const int nn = (n0 & 1023) + lc * 8;
      const int h = nn >> 6, d = nn & 63;
      const int b = gm >> 11, s = gm & 2047;
      bf16_t* dst = (n0 < 1024) ? ob0 : (n0 < 2048) ? ob1 : ob2;
      *(uint4*)&dst[(((size_t)b * 16 + h) * 2048 + s) * 64 + d] = v;
    } else if (MODE == MODE_FF1) {
      *(uint4*)&ob0[(size_t)gm * N + n0 + lc * 8] = v;
    } else {
      bf16_t* dst = (blockIdx.z == 2) ? ob1 : ob0 + (size_t)blockIdx.z * 4194304;
      *(uint4*)&dst[(size_t)gm * N + n0 + lc * 8] = v;
    }
  }
}

// ---------------------------------------------------------------------------
extern "C" void kernel_launch(void* const* d_in, const int* in_sizes, int n_in,
                              void* d_out, int out_size, void* d_ws, size_t ws_size,
                              hipStream_t stream) {
  const float* x = (const float*)d_in[0];
  const float* Wq = (const float*)d_in[1];
  const float* bq = (const float*)d_in[2];
  const float* Wk = (const float*)d_in[3];
  const float* bk = (const float*)d_in[4];
  const float* Wv = (const float*)d_in[5];
  const float* bv = (const float*)d_in[6];
  const float* Wo = (const float*)d_in[7];
  const float* bo = (const float*)d_in[8];
  const float* W1 = (const float*)d_in[9];
  const float* b1 = (const float*)d_in[10];
  const float* W2 = (const float*)d_in[11];
  const float* b2 = (const float*)d_in[12];
  const float* g1 = (const float*)d_in[13];
  const float* be1 = (const float*)d_in[14];
  const float* g2 = (const float*)d_in[15];
  const float* be2 = (const float*)d_in[16];
  float* out = (float*)d_out;

  char* ws = (char*)d_ws;
  size_t off = 0;
  auto alloc = [&](size_t bytes) {
    void* p = ws + off;
    off += (bytes + 255) & ~(size_t)255;
    return p;
  };
  bf16_t* WqkvT = (bf16_t*)alloc(3072ULL * 1024 * 2);  // [0,6MB)
  bf16_t* WoT = (bf16_t*)alloc(1024ULL * 1024 * 2);    // [6,8)
  bf16_t* W1T = (bf16_t*)alloc(4096ULL * 1024 * 2);    // [8,16)
  bf16_t* W2T = (bf16_t*)alloc(1024ULL * 4096 * 2);    // [16,24)
  bf16_t* xnb = (bf16_t*)alloc(4096ULL * 1024 * 2);    // [24,32)
  bf16_t* qb = (bf16_t*)alloc(4194304ULL * 2);         // [32,40)
  bf16_t* kb = (bf16_t*)alloc(4194304ULL * 2);         // [40,48)
  bf16_t* vraw = (bf16_t*)alloc(4194304ULL * 2);       // [48,56)
  bf16_t* vt = (bf16_t*)alloc(4194304ULL * 2);         // [56,64)
  bf16_t* h1 = qb;
  bf16_t* x2p = qb;
  bf16_t* ffp = WqkvT;
  float* x2 = (float*)alloc(16777216ULL);              // [64,80)

  static bool attrset = false;
  if (!attrset) {
    hipFuncSetAttribute((const void*)gemm_ff1_256,
                        hipFuncAttributeMaxDynamicSharedMemorySize, 131072);
    attrset = true;
  }

  prep_kernel<<<16384, 256, 0, stream>>>(Wq, Wk, Wv, Wo, W1, W2, x, g1, be1,
                                         WqkvT, W1T, W2T, xnb);

  gemm_bt<MODE_QKV><<<dim3(32, 24, 1), 256, 0, stream>>>(xnb, WqkvT, 4096, 3072, 1024, 1024,
                                                         bq, bk, bv, qb, kb, vraw);

  rope_bf16<<<8192, 256, 0, stream>>>(qb, kb);

  vtrans<<<dim3(32, 64, 2), 256, 0, stream>>>(vraw, vt);

  attn7<<<dim3(32, 16), 256, 0, stream>>>(qb, kb, vt, xnb);

  // X2 = attn_out @ Wo, split-K=4 (kspan 256)
  gemm_bt<MODE_PART><<<dim3(32, 8, 4), 256, 0, stream>>>(xnb, WoT, 4096, 1024, 1024, 256,
                                                         nullptr, nullptr, nullptr,
                                                         x2p, x2p + 2 * 4194304, nullptr);

  ln2_combine<<<4096, 256, 0, stream>>>(x2p, x, bo, g2, be2, x2, xnb);

  // FF1 via 8-phase 256^2 kernel
  gemm_ff1_256<<<dim3(16, 16), 512, 131072, stream>>>(xnb, W1T, b1, h1);

  // FF2 = h1 @ W2, split-K=3 (1408/1408/1280)
  gemm_bt<MODE_PART><<<dim3(32, 8, 3), 256, 0, stream>>>(h1, W2T, 4096, 1024, 4096, 1408,
                                                         nullptr, nullptr, nullptr,
                                                         ffp, xnb, nullptr);

  ffn_combine<<<4096, 256, 0, stream>>>(ffp, xnb, x2, b2, out);
}